// Round 12
// baseline (313.779 us; speedup 1.0000x reference)
//
#include <hip/hip_runtime.h>

// B=16, C=128, H=256, W=64.  Pipeline (workspace W-MAJOR: [b][w][h][c]):
//  K0: convert wq/wk/wv/wfc fp32->bf16 into ws tail (R8-validated)
//  K1: Q/K/V = relu(Wx+b) -> ws [b][w][h][c] bf16; 8KB quarter-staged row
//      writes, 40KB LDS -> 4 blocks/CU; weights prefetched before X-stage.
//  K2: per-(b,w) attention, 16 waves, 160KB (R8-validated, byte-identical)
//  K3: out = relu(wfc . att^T + bfc) (R8-validated, byte-identical)

typedef __attribute__((ext_vector_type(8))) short short8;
typedef __attribute__((ext_vector_type(4))) float f32x4;

#define MFMA16(acc, a, b) (acc) = __builtin_amdgcn_mfma_f32_16x16x32_bf16((a), (b), (acc), 0, 0, 0)

__device__ __forceinline__ unsigned short f2b(float f) {
  unsigned u = __builtin_bit_cast(unsigned, f);
  u = (u + 0x7fffu + ((u >> 16) & 1u)) >> 16;   // RNE
  return (unsigned short)u;
}

// [R][128c] bf16 tile, row-XOR swizzle (verified write-scalar/read-b128 pair)
__device__ __forceinline__ unsigned adr_s(int r, int c) {
  return (unsigned)(((r << 8) + (c << 1)) ^ ((r & 7) << 4));
}
// K1's XS [128j][128c]: stronger row-hash (rows written in stride-4 bursts)
__device__ __forceinline__ unsigned adr_q(int r, int c) {
  return (unsigned)(((r << 8) + (c << 1)) ^ (((r ^ (r >> 3)) & 7) << 4));
}
// V^T tile [128c][256g] (R5-verified double-XOR)
__device__ __forceinline__ unsigned adr_vt(int c, int g) {
  unsigned blk = (unsigned)(((g >> 3) ^ (c & 7) ^ ((c >> 3) & 7)) & 31);
  return (unsigned)((c << 9) + (blk << 4) + ((g & 7) << 1));
}
// per-wave P quarter-slice [16r][64c] bf16 (2KB), row-hash (R5-verified)
__device__ __forceinline__ unsigned ps_adr(int r, int c) {
  return (unsigned)(((r << 7) + (c << 1)) ^ (((r ^ (r >> 3)) & 7) << 4));
}

__device__ __forceinline__ short8 ldsf(const char* p, unsigned off) {
  return *(const short8*)(p + off);
}

// ================= K0: weight pre-convert fp32 -> bf16 =================
__global__ __launch_bounds__(256) void k0_wcvt(
    const float* __restrict__ wq, const float* __restrict__ wk,
    const float* __restrict__ wv, const float* __restrict__ wfc,
    unsigned short* __restrict__ wb)
{
  int i = blockIdx.x * 256 + threadIdx.x;    // 16384 float4's total
  int mat = i >> 12, off = (i & 4095) * 4;
  const float* src = (mat == 0) ? wq : (mat == 1) ? wk : (mat == 2) ? wv : wfc;
  float4 v = *(const float4*)(src + off);
  uint2 u;
  u.x = (unsigned)f2b(v.x) | ((unsigned)f2b(v.y) << 16);
  u.y = (unsigned)f2b(v.z) | ((unsigned)f2b(v.w) << 16);
  *(uint2*)(wb + mat * 16384 + off) = u;
}

// ================= K1: QKV projection =================
// grid = nbc*128; block tile = 128 n (n = h*64+w).
// LDS: XS [128n][128c] @0 (32K), WS quarter-stage [32n][128c] @32K (8K). 40K.
// Output W-MAJOR: dst[((brel*64+w)*256 + h)*128 + c].

__device__ __forceinline__ void k1_one(const short8* wf, const float* bv4,
    unsigned short* dst, const char* XS, char* WS,
    int brel, int n0, int wvid, int l, int l16, int g4) {
  f32x4 acc[8];
#pragma unroll
  for (int nt = 0; nt < 8; ++nt) acc[nt] = (f32x4){0.f, 0.f, 0.f, 0.f};
#pragma unroll
  for (int nt = 0; nt < 8; ++nt) {
#pragma unroll
    for (int kk = 0; kk < 4; ++kk) {
      short8 xb = ldsf(XS, adr_q(nt * 16 + l16, kk * 32 + g4 * 8));
      MFMA16(acc[nt], wf[kk], xb);   // D[o][n']: col=l16 -> n', row=g4*4+r -> o
    }
  }
  // four 32-row quarters through the 8K WS
#pragma unroll
  for (int qt = 0; qt < 4; ++qt) {
    __syncthreads();   // WS free (previous readback complete)
#pragma unroll
    for (int nt2 = 0; nt2 < 2; ++nt2) {
      int nt = qt * 2 + nt2;
      float y0 = fmaxf(acc[nt][0] + bv4[0], 0.f);
      float y1 = fmaxf(acc[nt][1] + bv4[1], 0.f);
      float y2 = fmaxf(acc[nt][2] + bv4[2], 0.f);
      float y3 = fmaxf(acc[nt][3] + bv4[3], 0.f);
      uint2 u;
      u.x = (unsigned)f2b(y0) | ((unsigned)f2b(y1) << 16);
      u.y = (unsigned)f2b(y2) | ((unsigned)f2b(y3) << 16);
      int row = nt2 * 16 + l16;                       // 0..31
      unsigned cb = (unsigned)(wvid * 32 + g4 * 8);
      *(uint2*)(WS + (unsigned)(row << 8) + (cb ^ ((unsigned)(row & 7) << 4))) = u;
    }
    __syncthreads();
    // readback full 256B rows -> w-major global rows
#pragma unroll
    for (int it = 0; it < 4; ++it) {
      int row = it * 8 + wvid;                        // 0..31
      unsigned u = *(const unsigned*)(WS + (unsigned)(row << 8) +
                                     (((unsigned)(l << 2)) ^ ((unsigned)(row & 7) << 4)));
      int n = n0 + qt * 32 + row;
      int h = n >> 6, w = n & 63;
      ((unsigned*)dst)[(size_t)((brel * 64 + w) * 256 + h) * 64 + l] = u;
    }
  }
}

__global__ __launch_bounds__(512, 4) void k1_qkv(
    const float* __restrict__ rep, const unsigned short* __restrict__ wb,
    const float* __restrict__ bq, const float* __restrict__ bk,
    const float* __restrict__ bv,
    unsigned short* __restrict__ qo, unsigned short* __restrict__ ko,
    unsigned short* __restrict__ vo, int b0)
{
  extern __shared__ char smem[];
  char* XS = smem;               // 32K
  char* WS = smem + (32 << 10);  // 8K

  const int t = threadIdx.x;
  const int wvid = t >> 6, l = t & 63, l16 = l & 15, g4 = l >> 4;
  const int brel = blockIdx.x >> 7;
  const int n0 = (blockIdx.x & 127) * 128;
  const int b = b0 + brel;
  const int strip = wvid * 16;

  // prefetch all weight fragments + biases (latency hides under X-stage)
  short8 wfq[4], wfk[4], wfv[4];
#pragma unroll
  for (int kk = 0; kk < 4; ++kk) {
    wfq[kk] = *(const short8*)(wb         + (strip + l16) * 128 + kk * 32 + g4 * 8);
    wfk[kk] = *(const short8*)(wb + 16384 + (strip + l16) * 128 + kk * 32 + g4 * 8);
    wfv[kk] = *(const short8*)(wb + 32768 + (strip + l16) * 128 + kk * 32 + g4 * 8);
  }
  float bq4[4], bk4[4], bv4[4];
#pragma unroll
  for (int r = 0; r < 4; ++r) {
    bq4[r] = bq[strip + g4 * 4 + r];
    bk4[r] = bk[strip + g4 * 4 + r];
    bv4[r] = bv[strip + g4 * 4 + r];
  }

  // stage X^T: rep[b][c][n0+j] -> XS[j][c]  (float4-coalesced reads)
#pragma unroll
  for (int it = 0; it < 8; ++it) {
    int i = it * 512 + t;
    int c = i >> 5, j4 = i & 31;
    float4 xv = *(const float4*)(rep + (size_t)(b * 128 + c) * 16384 + n0 + j4 * 4);
    float vv[4] = {xv.x, xv.y, xv.z, xv.w};
#pragma unroll
    for (int r = 0; r < 4; ++r)
      *(unsigned short*)(XS + adr_q(j4 * 4 + r, c)) = f2b(vv[r]);
  }
  __syncthreads();

  k1_one(wfq, bq4, qo, XS, WS, brel, n0, wvid, l, l16, g4);
  k1_one(wfk, bk4, ko, XS, WS, brel, n0, wvid, l, l16, g4);
  k1_one(wfv, bv4, vo, XS, WS, brel, n0, wvid, l, l16, g4);
}

// ================= K2: attention per (b,w) — R8-validated, byte-identical ====
// 1024 thr (16 waves), wave owns 16 h rows. LDS: KS 64K @0, VTS 64K @64K,
// PS quarter-slices @128K (16 waves x 2K = 32K). Total 160K.

__global__ __launch_bounds__(1024, 1) void k2_attn(
    const unsigned short* __restrict__ qws, const unsigned short* __restrict__ kws,
    const unsigned short* __restrict__ vws, unsigned short* __restrict__ aws)
{
  extern __shared__ char smem[];
  char* KS  = smem;
  char* VTS = smem + (64 << 10);

  const int t = threadIdx.x;
  const int wvid = t >> 6, l = t & 63, l16 = l & 15, g4 = l >> 4;
  char* PS = smem + (128 << 10) + (wvid << 11);

  const int brel = blockIdx.x >> 6;
  const int w = blockIdx.x & 63;
  const size_t wbase = (size_t)((brel * 64 + w)) * 256;   // row index of (b,w,h=0)

  const int hb = wvid * 16;

  // q loads first (contiguous 4KB/wave), overlap with staging below
  short8 qa[4];
#pragma unroll
  for (int kk = 0; kk < 4; ++kk)
    qa[kk] = *(const short8*)(qws + (wbase + hb + l16) * 128 + kk * 32 + g4 * 8);

  // stage K rows [g][c] — contiguous 64KB
#pragma unroll
  for (int it = 0; it < 4; ++it) {
    int i = it * 1024 + t;
    int g = i >> 4, c16 = i & 15;
    short8 kv = *(const short8*)(kws + (wbase + g) * 128 + c16 * 8);
    *(short8*)(KS + adr_s(g, c16 * 8)) = kv;
  }
  // stage V^T [c][g] — contiguous reads, scalar swizzled writes
#pragma unroll
  for (int it = 0; it < 4; ++it) {
    int i = it * 1024 + t;
    int g = i >> 4, c16 = i & 15;
    short8 vv = *(const short8*)(vws + (wbase + g) * 128 + c16 * 8);
#pragma unroll
    for (int j = 0; j < 8; ++j)
      *(unsigned short*)(VTS + adr_vt(c16 * 8 + j, g)) = (unsigned short)vv[j];
  }
  __syncthreads();

  const float SCL2 = 0.08838834764831845f * 1.4426950408889634f; // rsqrt(128)*log2e

  f32x4 sc[16];
#pragma unroll
  for (int gt = 0; gt < 16; ++gt) {
    f32x4 acc = {0.f, 0.f, 0.f, 0.f};
#pragma unroll
    for (int kk = 0; kk < 4; ++kk) {
      short8 kb = ldsf(KS, adr_s(gt * 16 + l16, kk * 32 + g4 * 8));
      MFMA16(acc, qa[kk], kb);
    }
    sc[gt] = acc;
  }
  float mx[4], rcps[4];
#pragma unroll
  for (int r = 0; r < 4; ++r) {
    float mm = sc[0][r];
#pragma unroll
    for (int gt = 1; gt < 16; ++gt) mm = fmaxf(mm, sc[gt][r]);
    mm = fmaxf(mm, __shfl_xor(mm, 1, 64));
    mm = fmaxf(mm, __shfl_xor(mm, 2, 64));
    mm = fmaxf(mm, __shfl_xor(mm, 4, 64));
    mm = fmaxf(mm, __shfl_xor(mm, 8, 64));
    mx[r] = mm;
  }
#pragma unroll
  for (int gt = 0; gt < 16; ++gt)
#pragma unroll
    for (int r = 0; r < 4; ++r)
      sc[gt][r] = exp2f((sc[gt][r] - mx[r]) * SCL2);
#pragma unroll
  for (int r = 0; r < 4; ++r) {
    float s = 0.f;
#pragma unroll
    for (int gt = 0; gt < 16; ++gt) s += sc[gt][r];
    s += __shfl_xor(s, 1, 64);
    s += __shfl_xor(s, 2, 64);
    s += __shfl_xor(s, 4, 64);
    s += __shfl_xor(s, 8, 64);
    rcps[r] = 1.0f / s;
  }

  f32x4 oacc[8];
#pragma unroll
  for (int nt = 0; nt < 8; ++nt) oacc[nt] = (f32x4){0.f, 0.f, 0.f, 0.f};
#pragma unroll
  for (int gh = 0; gh < 4; ++gh) {
#pragma unroll
    for (int gt4 = 0; gt4 < 4; ++gt4) {
      int gt = gh * 4 + gt4;
      int gc = gt4 * 16 + l16;
#pragma unroll
      for (int r = 0; r < 4; ++r)
        *(unsigned short*)(PS + ps_adr(g4 * 4 + r, gc)) = f2b(sc[gt][r]);
    }
#pragma unroll
    for (int kk2 = 0; kk2 < 2; ++kk2) {
      short8 pa = ldsf(PS, ps_adr(l16, kk2 * 32 + g4 * 8));
#pragma unroll
      for (int nt = 0; nt < 8; ++nt) {
        short8 vb = ldsf(VTS, adr_vt(nt * 16 + l16, gh * 64 + kk2 * 32 + g4 * 8));
        MFMA16(oacc[nt], pa, vb);
      }
    }
  }
  // att[w-major]: row (b,w,h) contiguous 256B; block writes contiguous 64KB
#pragma unroll
  for (int nt = 0; nt < 8; ++nt) {
#pragma unroll
    for (int r = 0; r < 4; ++r) {
      size_t idx = (wbase + hb + g4 * 4 + r) * 128 + nt * 16 + l16;
      aws[idx] = f2b(oacc[nt][r] * rcps[r]);
    }
  }
}

// ================= K3: out = relu(wfc . att^T + bfc) — R8-validated ==========
// grid = nbc*64; block tile = 256 n.  LDS: AS [256n][128c] (64K).

__global__ __launch_bounds__(512, 4) void k3_conv(
    const unsigned short* __restrict__ aws, const unsigned short* __restrict__ wb,
    const float* __restrict__ bfc, float* __restrict__ out, int b0)
{
  extern __shared__ char smem[];
  char* AS = smem;

  const int t = threadIdx.x;
  const int wvid = t >> 6, l = t & 63, l16 = l & 15, g4 = l >> 4;
  (void)l;
  const int brel = blockIdx.x >> 6;
  const int n0 = (blockIdx.x & 63) * 256;
  const int b = b0 + brel;

#pragma unroll
  for (int it = 0; it < 8; ++it) {
    int i = it * 512 + t;
    int nn = i >> 4, c16 = i & 15;
    int n = n0 + nn;
    int h = n >> 6, w = n & 63;
    short8 av = *(const short8*)(aws + ((size_t)((brel * 64 + w) * 256 + h)) * 128 + c16 * 8);
    *(short8*)(AS + adr_s(nn, c16 * 8)) = av;
  }
  __syncthreads();

  const int strip = wvid * 16;
  const unsigned short* wfcb = wb + 3 * 16384;
  short8 wf[4];
#pragma unroll
  for (int kk = 0; kk < 4; ++kk)
    wf[kk] = *(const short8*)(wfcb + (strip + l16) * 128 + kk * 32 + g4 * 8);
  float bv4[4];
#pragma unroll
  for (int r = 0; r < 4; ++r) bv4[r] = bfc[strip + g4 * 4 + r];

#pragma unroll
  for (int nt = 0; nt < 16; ++nt) {
    f32x4 acc = {0.f, 0.f, 0.f, 0.f};
#pragma unroll
    for (int kk = 0; kk < 4; ++kk) {
      short8 ab = ldsf(AS, adr_s(nt * 16 + l16, kk * 32 + g4 * 8));
      MFMA16(acc, wf[kk], ab);
    }
#pragma unroll
    for (int r = 0; r < 4; ++r) {
      int o = strip + g4 * 4 + r;
      out[(size_t)(b * 128 + o) * 16384 + n0 + nt * 16 + l16] = fmaxf(acc[r] + bv4[r], 0.f);
    }
  }
}

extern "C" void kernel_launch(void* const* d_in, const int* in_sizes, int n_in,
                              void* d_out, int out_size, void* d_ws, size_t ws_size,
                              hipStream_t stream) {
  const float* rep = (const float*)d_in[0];
  const float* wq  = (const float*)d_in[1];
  const float* bq  = (const float*)d_in[2];
  const float* wk  = (const float*)d_in[3];
  const float* bk  = (const float*)d_in[4];
  const float* wv  = (const float*)d_in[5];
  const float* bv  = (const float*)d_in[6];
  const float* wfc = (const float*)d_in[7];
  const float* bfc = (const float*)d_in[8];
  float* out = (float*)d_out;
  (void)in_sizes; (void)n_in; (void)out_size;

  hipFuncSetAttribute((const void*)k1_qkv,  hipFuncAttributeMaxDynamicSharedMemorySize, 40 * 1024);
  hipFuncSetAttribute((const void*)k2_attn, hipFuncAttributeMaxDynamicSharedMemorySize, 160 * 1024);
  hipFuncSetAttribute((const void*)k3_conv, hipFuncAttributeMaxDynamicSharedMemorySize, 64 * 1024);

  const size_t wb_bytes = 4 * 16384 * 2;          // 128 KB bf16 weights
  const size_t per_b = (size_t)16384 * 128 * 2;   // 4 MiB per array per b
  if (ws_size < wb_bytes + 4 * per_b) return;     // needs >= ~16.1 MB
  size_t nb_max = (ws_size - wb_bytes) / (4 * per_b);
  int nb = (int)(nb_max < 16 ? nb_max : 16);

  char* ws = (char*)d_ws;
  unsigned short* qws = (unsigned short*)(ws);
  unsigned short* kws = (unsigned short*)(ws + (size_t)nb * per_b);
  unsigned short* vws = (unsigned short*)(ws + (size_t)nb * per_b * 2);
  unsigned short* aws = (unsigned short*)(ws + (size_t)nb * per_b * 3);
  unsigned short* wb  = (unsigned short*)(ws + (size_t)nb * per_b * 4);

  k0_wcvt<<<dim3(64), dim3(256), 0, stream>>>(wq, wk, wv, wfc, wb);

  for (int b0 = 0; b0 < 16; b0 += nb) {
    int nbc = (16 - b0) < nb ? (16 - b0) : nb;
    k1_qkv<<<dim3(nbc * 128), dim3(512), 40 * 1024, stream>>>(
        rep, wb, bq, bk, bv, qws, kws, vws, b0);
    k2_attn<<<dim3(nbc * 64), dim3(1024), 160 * 1024, stream>>>(qws, kws, vws, aws);
    k3_conv<<<dim3(nbc * 64), dim3(512), 64 * 1024, stream>>>(aws, wb, bfc, out, b0);
  }
}

// Round 14
// 247.915 us; speedup vs baseline: 1.2657x; 1.2657x over previous
//
#include <hip/hip_runtime.h>

// B=16, C=128, H=256, W=64.  Pipeline (workspace W-MAJOR: [b][w][h][c]):
//  K0: convert wq/wk/wv/wfc fp32->bf16 into ws tail (R8-validated)
//  K1: Q/K/V = relu(Wx+b) -> ws bf16; 16KB half-staged rows (R8-validated)
//  K2: per-(b,w) attention, 16 waves, 160KB (R8-validated) + coalesced att
//      stores via wave-private PS round-trip with TBAA-LEGAL ushort readback
//      (R13 bug: ushort-store -> uint-load may not alias => compiler hoisted
//       the loads above the stores; ushort->ushort is ordered).
//  K3: out = relu(wfc . att^T + bfc) (R8-validated)

typedef __attribute__((ext_vector_type(8))) short short8;
typedef __attribute__((ext_vector_type(4))) float f32x4;

#define MFMA16(acc, a, b) (acc) = __builtin_amdgcn_mfma_f32_16x16x32_bf16((a), (b), (acc), 0, 0, 0)

__device__ __forceinline__ unsigned short f2b(float f) {
  unsigned u = __builtin_bit_cast(unsigned, f);
  u = (u + 0x7fffu + ((u >> 16) & 1u)) >> 16;   // RNE
  return (unsigned short)u;
}

// [R][128c] bf16 tile, row-XOR swizzle (verified write-scalar/read-b128 pair)
__device__ __forceinline__ unsigned adr_s(int r, int c) {
  return (unsigned)(((r << 8) + (c << 1)) ^ ((r & 7) << 4));
}
// K1's XS [128j][128c]: stronger row-hash (rows written in stride-4 bursts)
__device__ __forceinline__ unsigned adr_q(int r, int c) {
  return (unsigned)(((r << 8) + (c << 1)) ^ (((r ^ (r >> 3)) & 7) << 4));
}
// V^T tile [128c][256g] (R5-verified double-XOR)
__device__ __forceinline__ unsigned adr_vt(int c, int g) {
  unsigned blk = (unsigned)(((g >> 3) ^ (c & 7) ^ ((c >> 3) & 7)) & 31);
  return (unsigned)((c << 9) + (blk << 4) + ((g & 7) << 1));
}
// per-wave P quarter-slice [16r][64c] bf16 (2KB), row-hash (R5-verified)
__device__ __forceinline__ unsigned ps_adr(int r, int c) {
  return (unsigned)(((r << 7) + (c << 1)) ^ (((r ^ (r >> 3)) & 7) << 4));
}

__device__ __forceinline__ short8 ldsf(const char* p, unsigned off) {
  return *(const short8*)(p + off);
}

// ================= K0: weight pre-convert fp32 -> bf16 =================
__global__ __launch_bounds__(256) void k0_wcvt(
    const float* __restrict__ wq, const float* __restrict__ wk,
    const float* __restrict__ wv, const float* __restrict__ wfc,
    unsigned short* __restrict__ wb)
{
  int i = blockIdx.x * 256 + threadIdx.x;    // 16384 float4's total
  int mat = i >> 12, off = (i & 4095) * 4;
  const float* src = (mat == 0) ? wq : (mat == 1) ? wk : (mat == 2) ? wv : wfc;
  float4 v = *(const float4*)(src + off);
  uint2 u;
  u.x = (unsigned)f2b(v.x) | ((unsigned)f2b(v.y) << 16);
  u.y = (unsigned)f2b(v.z) | ((unsigned)f2b(v.w) << 16);
  *(uint2*)(wb + mat * 16384 + off) = u;
}

// ================= K1: QKV projection (R8-validated, byte-identical) ==========
// grid = nbc*128; block tile = 128 n (n = h*64+w).
// LDS: XS [128n][128c] @0 (32K), WS half-stage [64n][128c] @32K (16K). 48K.
// Output W-MAJOR: dst[((brel*64+w)*256 + h)*128 + c].

__device__ __forceinline__ void k1_one(const unsigned short* wmat, const float* bias,
    unsigned short* dst, const char* XS, char* WS,
    int brel, int n0, int wvid, int l, int l16, int g4) {
  const int strip = wvid * 16;
  short8 wf[4];
#pragma unroll
  for (int kk = 0; kk < 4; ++kk)
    wf[kk] = *(const short8*)(wmat + (strip + l16) * 128 + kk * 32 + g4 * 8);
  float bv4[4];
#pragma unroll
  for (int r = 0; r < 4; ++r) bv4[r] = bias[strip + g4 * 4 + r];

  f32x4 acc[8];
#pragma unroll
  for (int nt = 0; nt < 8; ++nt) acc[nt] = (f32x4){0.f, 0.f, 0.f, 0.f};
#pragma unroll
  for (int nt = 0; nt < 8; ++nt) {
#pragma unroll
    for (int kk = 0; kk < 4; ++kk) {
      short8 xb = ldsf(XS, adr_q(nt * 16 + l16, kk * 32 + g4 * 8));
      MFMA16(acc[nt], wf[kk], xb);   // D[o][n']: col=l16 -> n', row=g4*4+r -> o
    }
  }
  // two 64-row halves through the 16K WS
#pragma unroll
  for (int hf = 0; hf < 2; ++hf) {
    __syncthreads();   // WS free (previous readback complete)
#pragma unroll
    for (int nt4 = 0; nt4 < 4; ++nt4) {
      int nt = hf * 4 + nt4;
      float y0 = fmaxf(acc[nt][0] + bv4[0], 0.f);
      float y1 = fmaxf(acc[nt][1] + bv4[1], 0.f);
      float y2 = fmaxf(acc[nt][2] + bv4[2], 0.f);
      float y3 = fmaxf(acc[nt][3] + bv4[3], 0.f);
      uint2 u;
      u.x = (unsigned)f2b(y0) | ((unsigned)f2b(y1) << 16);
      u.y = (unsigned)f2b(y2) | ((unsigned)f2b(y3) << 16);
      int row = nt4 * 16 + l16;                       // 0..63
      unsigned cb = (unsigned)(wvid * 32 + g4 * 8);
      *(uint2*)(WS + (unsigned)(row << 8) + (cb ^ ((unsigned)(row & 7) << 4))) = u;
    }
    __syncthreads();
    // readback full 256B rows -> w-major global rows
#pragma unroll
    for (int it = 0; it < 8; ++it) {
      int row = it * 8 + wvid;                        // 0..63
      unsigned u = *(const unsigned*)(WS + (unsigned)(row << 8) +
                                     (((unsigned)(l << 2)) ^ ((unsigned)(row & 7) << 4)));
      int n = n0 + hf * 64 + row;
      int h = n >> 6, w = n & 63;
      ((unsigned*)dst)[(size_t)((brel * 64 + w) * 256 + h) * 64 + l] = u;
    }
  }
}

__global__ __launch_bounds__(512, 4) void k1_qkv(
    const float* __restrict__ rep, const unsigned short* __restrict__ wb,
    const float* __restrict__ bq, const float* __restrict__ bk,
    const float* __restrict__ bv,
    unsigned short* __restrict__ qo, unsigned short* __restrict__ ko,
    unsigned short* __restrict__ vo, int b0)
{
  extern __shared__ char smem[];
  char* XS = smem;               // 32K
  char* WS = smem + (32 << 10);  // 16K

  const int t = threadIdx.x;
  const int wvid = t >> 6, l = t & 63, l16 = l & 15, g4 = l >> 4;
  const int brel = blockIdx.x >> 7;
  const int n0 = (blockIdx.x & 127) * 128;
  const int b = b0 + brel;

#pragma unroll
  for (int it = 0; it < 8; ++it) {
    int i = it * 512 + t;
    int c = i >> 5, j4 = i & 31;
    float4 xv = *(const float4*)(rep + (size_t)(b * 128 + c) * 16384 + n0 + j4 * 4);
    float vv[4] = {xv.x, xv.y, xv.z, xv.w};
#pragma unroll
    for (int r = 0; r < 4; ++r)
      *(unsigned short*)(XS + adr_q(j4 * 4 + r, c)) = f2b(vv[r]);
  }
  __syncthreads();

  k1_one(wb,         bq, qo, XS, WS, brel, n0, wvid, l, l16, g4);
  k1_one(wb + 16384, bk, ko, XS, WS, brel, n0, wvid, l, l16, g4);
  k1_one(wb + 32768, bv, vo, XS, WS, brel, n0, wvid, l, l16, g4);
}

// ================= K2: attention per (b,w) =================
// 1024 thr (16 waves), wave owns 16 h rows. LDS: KS 64K @0, VTS 64K @64K,
// PS quarter-slices @128K (16 waves x 2K = 32K). Total 160K.

__global__ __launch_bounds__(1024, 1) void k2_attn(
    const unsigned short* __restrict__ qws, const unsigned short* __restrict__ kws,
    const unsigned short* __restrict__ vws, unsigned short* __restrict__ aws)
{
  extern __shared__ char smem[];
  char* KS  = smem;
  char* VTS = smem + (64 << 10);

  const int t = threadIdx.x;
  const int wvid = t >> 6, l = t & 63, l16 = l & 15, g4 = l >> 4;
  char* PS = smem + (128 << 10) + (wvid << 11);

  const int brel = blockIdx.x >> 6;
  const int w = blockIdx.x & 63;
  const size_t wbase = (size_t)((brel * 64 + w)) * 256;   // row index of (b,w,h=0)

  const int hb = wvid * 16;

  // q loads first (contiguous 4KB/wave), overlap with staging below
  short8 qa[4];
#pragma unroll
  for (int kk = 0; kk < 4; ++kk)
    qa[kk] = *(const short8*)(qws + (wbase + hb + l16) * 128 + kk * 32 + g4 * 8);

  // stage K rows [g][c] — contiguous 64KB
#pragma unroll
  for (int it = 0; it < 4; ++it) {
    int i = it * 1024 + t;
    int g = i >> 4, c16 = i & 15;
    short8 kv = *(const short8*)(kws + (wbase + g) * 128 + c16 * 8);
    *(short8*)(KS + adr_s(g, c16 * 8)) = kv;
  }
  // stage V^T [c][g] — contiguous reads, scalar swizzled writes
#pragma unroll
  for (int it = 0; it < 4; ++it) {
    int i = it * 1024 + t;
    int g = i >> 4, c16 = i & 15;
    short8 vv = *(const short8*)(vws + (wbase + g) * 128 + c16 * 8);
#pragma unroll
    for (int j = 0; j < 8; ++j)
      *(unsigned short*)(VTS + adr_vt(c16 * 8 + j, g)) = (unsigned short)vv[j];
  }
  __syncthreads();

  const float SCL2 = 0.08838834764831845f * 1.4426950408889634f; // rsqrt(128)*log2e

  f32x4 sc[16];
#pragma unroll
  for (int gt = 0; gt < 16; ++gt) {
    f32x4 acc = {0.f, 0.f, 0.f, 0.f};
#pragma unroll
    for (int kk = 0; kk < 4; ++kk) {
      short8 kb = ldsf(KS, adr_s(gt * 16 + l16, kk * 32 + g4 * 8));
      MFMA16(acc, qa[kk], kb);
    }
    sc[gt] = acc;
  }
  float mx[4], rcps[4];
#pragma unroll
  for (int r = 0; r < 4; ++r) {
    float mm = sc[0][r];
#pragma unroll
    for (int gt = 1; gt < 16; ++gt) mm = fmaxf(mm, sc[gt][r]);
    mm = fmaxf(mm, __shfl_xor(mm, 1, 64));
    mm = fmaxf(mm, __shfl_xor(mm, 2, 64));
    mm = fmaxf(mm, __shfl_xor(mm, 4, 64));
    mm = fmaxf(mm, __shfl_xor(mm, 8, 64));
    mx[r] = mm;
  }
#pragma unroll
  for (int gt = 0; gt < 16; ++gt)
#pragma unroll
    for (int r = 0; r < 4; ++r)
      sc[gt][r] = exp2f((sc[gt][r] - mx[r]) * SCL2);
#pragma unroll
  for (int r = 0; r < 4; ++r) {
    float s = 0.f;
#pragma unroll
    for (int gt = 0; gt < 16; ++gt) s += sc[gt][r];
    s += __shfl_xor(s, 1, 64);
    s += __shfl_xor(s, 2, 64);
    s += __shfl_xor(s, 4, 64);
    s += __shfl_xor(s, 8, 64);
    rcps[r] = 1.0f / s;
  }

  f32x4 oacc[8];
#pragma unroll
  for (int nt = 0; nt < 8; ++nt) oacc[nt] = (f32x4){0.f, 0.f, 0.f, 0.f};
#pragma unroll
  for (int gh = 0; gh < 4; ++gh) {
#pragma unroll
    for (int gt4 = 0; gt4 < 4; ++gt4) {
      int gt = gh * 4 + gt4;
      int gc = gt4 * 16 + l16;
#pragma unroll
      for (int r = 0; r < 4; ++r)
        *(unsigned short*)(PS + ps_adr(g4 * 4 + r, gc)) = f2b(sc[gt][r]);
    }
#pragma unroll
    for (int kk2 = 0; kk2 < 2; ++kk2) {
      short8 pa = ldsf(PS, ps_adr(l16, kk2 * 32 + g4 * 8));
#pragma unroll
      for (int nt = 0; nt < 8; ++nt) {
        short8 vb = ldsf(VTS, adr_vt(nt * 16 + l16, gh * 64 + kk2 * 32 + g4 * 8));
        MFMA16(oacc[nt], pa, vb);
      }
    }
  }

  // att stores, coalesced: [16h][64c] halves through wave-private PS.
  // Readback via unsigned short (SAME type as stores -> may-alias -> ordered;
  // R13's uint readback was TBAA-reordered above the stores).
#pragma unroll
  for (int ch = 0; ch < 2; ++ch) {
#pragma unroll
    for (int nt4 = 0; nt4 < 4; ++nt4) {
      int nt = ch * 4 + nt4;
#pragma unroll
      for (int r = 0; r < 4; ++r)
        *(unsigned short*)(PS + ps_adr(g4 * 4 + r, nt4 * 16 + l16)) =
            f2b(oacc[nt][r] * rcps[r]);
    }
#pragma unroll
    for (int it = 0; it < 8; ++it) {
      int row = it * 2 + (l >> 5);   // 0..15
      int cd  = l & 31;              // dword within 128B row-half
      unsigned base = (unsigned)(row << 7) +
          (((unsigned)(cd << 2)) ^ (((unsigned)((row ^ (row >> 3)) & 7)) << 4));
      unsigned lo = *(const unsigned short*)(PS + base);
      unsigned hi = *(const unsigned short*)(PS + base + 2);
      ((unsigned*)aws)[(wbase + hb + row) * 64 + ch * 32 + cd] = lo | (hi << 16);
    }
  }
}

// ================= K3: out = relu(wfc . att^T + bfc) — R8-validated ==========
// grid = nbc*64; block tile = 256 n.  LDS: AS [256n][128c] (64K).

__global__ __launch_bounds__(512, 4) void k3_conv(
    const unsigned short* __restrict__ aws, const unsigned short* __restrict__ wb,
    const float* __restrict__ bfc, float* __restrict__ out, int b0)
{
  extern __shared__ char smem[];
  char* AS = smem;

  const int t = threadIdx.x;
  const int wvid = t >> 6, l = t & 63, l16 = l & 15, g4 = l >> 4;
  (void)l;
  const int brel = blockIdx.x >> 6;
  const int n0 = (blockIdx.x & 63) * 256;
  const int b = b0 + brel;

#pragma unroll
  for (int it = 0; it < 8; ++it) {
    int i = it * 512 + t;
    int nn = i >> 4, c16 = i & 15;
    int n = n0 + nn;
    int h = n >> 6, w = n & 63;
    short8 av = *(const short8*)(aws + ((size_t)((brel * 64 + w) * 256 + h)) * 128 + c16 * 8);
    *(short8*)(AS + adr_s(nn, c16 * 8)) = av;
  }
  __syncthreads();

  const int strip = wvid * 16;
  const unsigned short* wfcb = wb + 3 * 16384;
  short8 wf[4];
#pragma unroll
  for (int kk = 0; kk < 4; ++kk)
    wf[kk] = *(const short8*)(wfcb + (strip + l16) * 128 + kk * 32 + g4 * 8);
  float bv4[4];
#pragma unroll
  for (int r = 0; r < 4; ++r) bv4[r] = bfc[strip + g4 * 4 + r];

#pragma unroll
  for (int nt = 0; nt < 16; ++nt) {
    f32x4 acc = {0.f, 0.f, 0.f, 0.f};
#pragma unroll
    for (int kk = 0; kk < 4; ++kk) {
      short8 ab = ldsf(AS, adr_s(nt * 16 + l16, kk * 32 + g4 * 8));
      MFMA16(acc, wf[kk], ab);
    }
#pragma unroll
    for (int r = 0; r < 4; ++r) {
      int o = strip + g4 * 4 + r;
      out[(size_t)(b * 128 + o) * 16384 + n0 + nt * 16 + l16] = fmaxf(acc[r] + bv4[r], 0.f);
    }
  }
}

extern "C" void kernel_launch(void* const* d_in, const int* in_sizes, int n_in,
                              void* d_out, int out_size, void* d_ws, size_t ws_size,
                              hipStream_t stream) {
  const float* rep = (const float*)d_in[0];
  const float* wq  = (const float*)d_in[1];
  const float* bq  = (const float*)d_in[2];
  const float* wk  = (const float*)d_in[3];
  const float* bk  = (const float*)d_in[4];
  const float* wv  = (const float*)d_in[5];
  const float* bv  = (const float*)d_in[6];
  const float* wfc = (const float*)d_in[7];
  const float* bfc = (const float*)d_in[8];
  float* out = (float*)d_out;
  (void)in_sizes; (void)n_in; (void)out_size;

  hipFuncSetAttribute((const void*)k1_qkv,  hipFuncAttributeMaxDynamicSharedMemorySize, 48 * 1024);
  hipFuncSetAttribute((const void*)k2_attn, hipFuncAttributeMaxDynamicSharedMemorySize, 160 * 1024);
  hipFuncSetAttribute((const void*)k3_conv, hipFuncAttributeMaxDynamicSharedMemorySize, 64 * 1024);

  const size_t wb_bytes = 4 * 16384 * 2;          // 128 KB bf16 weights
  const size_t per_b = (size_t)16384 * 128 * 2;   // 4 MiB per array per b
  if (ws_size < wb_bytes + 4 * per_b) return;     // needs >= ~16.1 MB
  size_t nb_max = (ws_size - wb_bytes) / (4 * per_b);
  int nb = (int)(nb_max < 16 ? nb_max : 16);

  char* ws = (char*)d_ws;
  unsigned short* qws = (unsigned short*)(ws);
  unsigned short* kws = (unsigned short*)(ws + (size_t)nb * per_b);
  unsigned short* vws = (unsigned short*)(ws + (size_t)nb * per_b * 2);
  unsigned short* aws = (unsigned short*)(ws + (size_t)nb * per_b * 3);
  unsigned short* wb  = (unsigned short*)(ws + (size_t)nb * per_b * 4);

  k0_wcvt<<<dim3(64), dim3(256), 0, stream>>>(wq, wk, wv, wfc, wb);

  for (int b0 = 0; b0 < 16; b0 += nb) {
    int nbc = (16 - b0) < nb ? (16 - b0) : nb;
    k1_qkv<<<dim3(nbc * 128), dim3(512), 48 * 1024, stream>>>(
        rep, wb, bq, bk, bv, qws, kws, vws, b0);
    k2_attn<<<dim3(nbc * 64), dim3(1024), 160 * 1024, stream>>>(qws, kws, vws, aws);
    k3_conv<<<dim3(nbc * 64), dim3(512), 64 * 1024, stream>>>(aws, wb, bfc, out, b0);
  }
}

// Round 15
// 234.363 us; speedup vs baseline: 1.3389x; 1.0578x over previous
//
#include <hip/hip_runtime.h>

// B=16, C=128, H=256, W=64.  Pipeline (workspace W-MAJOR: [b][w][h][c]):
//  K0: convert wq/wk/wv/wfc fp32->bf16 into ws tail (R8-validated)
//  K1: Q/K/V = relu(Wx+b) -> ws bf16; 16KB half-staged rows (R8-validated)
//  K2: per-(b,w) attention; K rows PERMUTED in LDS so swapped QK^T leaves a
//      full P-row per lane -> softmax in-lane, P never touches LDS (f2b only,
//      no cvtpk/bpermute). att stores via R14-validated PS round-trip.
//  K3: out = relu(wfc . att^T + bfc) (R8-validated)

typedef __attribute__((ext_vector_type(8))) short short8;
typedef __attribute__((ext_vector_type(4))) float f32x4;
typedef __attribute__((ext_vector_type(4))) int int4v;

#define MFMA16(acc, a, b) (acc) = __builtin_amdgcn_mfma_f32_16x16x32_bf16((a), (b), (acc), 0, 0, 0)

__device__ __forceinline__ unsigned short f2b(float f) {
  unsigned u = __builtin_bit_cast(unsigned, f);
  u = (u + 0x7fffu + ((u >> 16) & 1u)) >> 16;   // RNE
  return (unsigned short)u;
}

// [R][128c] bf16 tile, row-XOR swizzle (verified write-scalar/read-b128 pair)
__device__ __forceinline__ unsigned adr_s(int r, int c) {
  return (unsigned)(((r << 8) + (c << 1)) ^ ((r & 7) << 4));
}
// K1's XS [128j][128c]: stronger row-hash (rows written in stride-4 bursts)
__device__ __forceinline__ unsigned adr_q(int r, int c) {
  return (unsigned)(((r << 8) + (c << 1)) ^ (((r ^ (r >> 3)) & 7) << 4));
}
// V^T tile [128c][256g] (R5-verified double-XOR)
__device__ __forceinline__ unsigned adr_vt(int c, int g) {
  unsigned blk = (unsigned)(((g >> 3) ^ (c & 7) ^ ((c >> 3) & 7)) & 31);
  return (unsigned)((c << 9) + (blk << 4) + ((g & 7) << 1));
}
// per-wave P/att slice [16r][64c] bf16 (2KB), row-hash (R5-verified)
__device__ __forceinline__ unsigned ps_adr(int r, int c) {
  return (unsigned)(((r << 7) + (c << 1)) ^ (((r ^ (r >> 3)) & 7) << 4));
}

__device__ __forceinline__ short8 ldsf(const char* p, unsigned off) {
  return *(const short8*)(p + off);
}

// ================= K0: weight pre-convert fp32 -> bf16 =================
__global__ __launch_bounds__(256) void k0_wcvt(
    const float* __restrict__ wq, const float* __restrict__ wk,
    const float* __restrict__ wv, const float* __restrict__ wfc,
    unsigned short* __restrict__ wb)
{
  int i = blockIdx.x * 256 + threadIdx.x;    // 16384 float4's total
  int mat = i >> 12, off = (i & 4095) * 4;
  const float* src = (mat == 0) ? wq : (mat == 1) ? wk : (mat == 2) ? wv : wfc;
  float4 v = *(const float4*)(src + off);
  uint2 u;
  u.x = (unsigned)f2b(v.x) | ((unsigned)f2b(v.y) << 16);
  u.y = (unsigned)f2b(v.z) | ((unsigned)f2b(v.w) << 16);
  *(uint2*)(wb + mat * 16384 + off) = u;
}

// ================= K1: QKV projection (R8-validated, byte-identical) ==========
// grid = nbc*128; block tile = 128 n (n = h*64+w).
// LDS: XS [128n][128c] @0 (32K), WS half-stage [64n][128c] @32K (16K). 48K.
// Output W-MAJOR: dst[((brel*64+w)*256 + h)*128 + c].

__device__ __forceinline__ void k1_one(const unsigned short* wmat, const float* bias,
    unsigned short* dst, const char* XS, char* WS,
    int brel, int n0, int wvid, int l, int l16, int g4) {
  const int strip = wvid * 16;
  short8 wf[4];
#pragma unroll
  for (int kk = 0; kk < 4; ++kk)
    wf[kk] = *(const short8*)(wmat + (strip + l16) * 128 + kk * 32 + g4 * 8);
  float bv4[4];
#pragma unroll
  for (int r = 0; r < 4; ++r) bv4[r] = bias[strip + g4 * 4 + r];

  f32x4 acc[8];
#pragma unroll
  for (int nt = 0; nt < 8; ++nt) acc[nt] = (f32x4){0.f, 0.f, 0.f, 0.f};
#pragma unroll
  for (int nt = 0; nt < 8; ++nt) {
#pragma unroll
    for (int kk = 0; kk < 4; ++kk) {
      short8 xb = ldsf(XS, adr_q(nt * 16 + l16, kk * 32 + g4 * 8));
      MFMA16(acc[nt], wf[kk], xb);   // D[o][n']: col=l16 -> n', row=g4*4+r -> o
    }
  }
  // two 64-row halves through the 16K WS
#pragma unroll
  for (int hf = 0; hf < 2; ++hf) {
    __syncthreads();   // WS free (previous readback complete)
#pragma unroll
    for (int nt4 = 0; nt4 < 4; ++nt4) {
      int nt = hf * 4 + nt4;
      float y0 = fmaxf(acc[nt][0] + bv4[0], 0.f);
      float y1 = fmaxf(acc[nt][1] + bv4[1], 0.f);
      float y2 = fmaxf(acc[nt][2] + bv4[2], 0.f);
      float y3 = fmaxf(acc[nt][3] + bv4[3], 0.f);
      uint2 u;
      u.x = (unsigned)f2b(y0) | ((unsigned)f2b(y1) << 16);
      u.y = (unsigned)f2b(y2) | ((unsigned)f2b(y3) << 16);
      int row = nt4 * 16 + l16;                       // 0..63
      unsigned cb = (unsigned)(wvid * 32 + g4 * 8);
      *(uint2*)(WS + (unsigned)(row << 8) + (cb ^ ((unsigned)(row & 7) << 4))) = u;
    }
    __syncthreads();
    // readback full 256B rows -> w-major global rows
#pragma unroll
    for (int it = 0; it < 8; ++it) {
      int row = it * 8 + wvid;                        // 0..63
      unsigned u = *(const unsigned*)(WS + (unsigned)(row << 8) +
                                     (((unsigned)(l << 2)) ^ ((unsigned)(row & 7) << 4)));
      int n = n0 + hf * 64 + row;
      int h = n >> 6, w = n & 63;
      ((unsigned*)dst)[(size_t)((brel * 64 + w) * 256 + h) * 64 + l] = u;
    }
  }
}

__global__ __launch_bounds__(512, 4) void k1_qkv(
    const float* __restrict__ rep, const unsigned short* __restrict__ wb,
    const float* __restrict__ bq, const float* __restrict__ bk,
    const float* __restrict__ bv,
    unsigned short* __restrict__ qo, unsigned short* __restrict__ ko,
    unsigned short* __restrict__ vo, int b0)
{
  extern __shared__ char smem[];
  char* XS = smem;               // 32K
  char* WS = smem + (32 << 10);  // 16K

  const int t = threadIdx.x;
  const int wvid = t >> 6, l = t & 63, l16 = l & 15, g4 = l >> 4;
  const int brel = blockIdx.x >> 7;
  const int n0 = (blockIdx.x & 127) * 128;
  const int b = b0 + brel;

#pragma unroll
  for (int it = 0; it < 8; ++it) {
    int i = it * 512 + t;
    int c = i >> 5, j4 = i & 31;
    float4 xv = *(const float4*)(rep + (size_t)(b * 128 + c) * 16384 + n0 + j4 * 4);
    float vv[4] = {xv.x, xv.y, xv.z, xv.w};
#pragma unroll
    for (int r = 0; r < 4; ++r)
      *(unsigned short*)(XS + adr_q(j4 * 4 + r, c)) = f2b(vv[r]);
  }
  __syncthreads();

  k1_one(wb,         bq, qo, XS, WS, brel, n0, wvid, l, l16, g4);
  k1_one(wb + 16384, bk, ko, XS, WS, brel, n0, wvid, l, l16, g4);
  k1_one(wb + 32768, bv, vo, XS, WS, brel, n0, wvid, l, l16, g4);
}

// ================= K2: attention per (b,w), permuted-K swapped QK^T ==========
// 1024 thr (16 waves), wave owns 16 h rows. LDS: KS 64K @0, VTS 64K @64K,
// PS att-store slices @128K (16 x 2K). Total 160K.
// K row g at position p(g)=32(g>>5)|16((g>>2)&1)|4((g>>3)&3)|(g&3) (bijective).
// Swapped MFMA(K,Q): lane (l16,g4) reg (gt,r) holds P[h=hb+l16][g=32(gt>>1)+
// 8*g4+4*(gt&1)+r] -> full P-row per lane. PV A-frag needs g=32*kks+8*g4+j;
// since 4*(j>>2)+(j&3)=j, pa={pk0[2kks],pk1[2kks],pk0[2kks+1],pk1[2kks+1]}
// is exactly lane-local. No P LDS traffic, no cross-lane P movement.

__global__ __launch_bounds__(1024, 1) void k2_attn(
    const unsigned short* __restrict__ qws, const unsigned short* __restrict__ kws,
    const unsigned short* __restrict__ vws, unsigned short* __restrict__ aws)
{
  extern __shared__ char smem[];
  char* KS  = smem;
  char* VTS = smem + (64 << 10);

  const int t = threadIdx.x;
  const int wvid = t >> 6, l = t & 63, l16 = l & 15, g4 = l >> 4;
  char* PS = smem + (128 << 10) + (wvid << 11);

  const int brel = blockIdx.x >> 6;
  const int w = blockIdx.x & 63;
  const size_t wbase = (size_t)((brel * 64 + w)) * 256;   // row index of (b,w,h=0)

  const int hb = wvid * 16;

  // q rows (lane's own h = hb+l16), contiguous reads
  short8 qa[4];
#pragma unroll
  for (int kk = 0; kk < 4; ++kk)
    qa[kk] = *(const short8*)(qws + (wbase + hb + l16) * 128 + kk * 32 + g4 * 8);

  // stage K rows [g][c] at permuted position p(g) — contiguous global reads
#pragma unroll
  for (int it = 0; it < 4; ++it) {
    int i = it * 1024 + t;
    int g = i >> 4, c16 = i & 15;
    int gp = (g & ~31) | ((g & 4) << 2) | ((g >> 1) & 12) | (g & 3);
    short8 kv = *(const short8*)(kws + (wbase + g) * 128 + c16 * 8);
    *(short8*)(KS + adr_s(gp, c16 * 8)) = kv;
  }
  // stage V^T [c][g] — contiguous reads, scalar swizzled writes (natural g)
#pragma unroll
  for (int it = 0; it < 4; ++it) {
    int i = it * 1024 + t;
    int g = i >> 4, c16 = i & 15;
    short8 vv = *(const short8*)(vws + (wbase + g) * 128 + c16 * 8);
#pragma unroll
    for (int j = 0; j < 8; ++j)
      *(unsigned short*)(VTS + adr_vt(c16 * 8 + j, g)) = (unsigned short)vv[j];
  }
  __syncthreads();

  const float SCL2 = 0.08838834764831845f * 1.4426950408889634f; // rsqrt(128)*log2e

  // swapped scores: A = K position rows, B = Q rows (lane's h column)
  f32x4 sc[16];
#pragma unroll
  for (int gt = 0; gt < 16; ++gt) {
    f32x4 acc = {0.f, 0.f, 0.f, 0.f};
#pragma unroll
    for (int kk = 0; kk < 4; ++kk) {
      short8 kb = ldsf(KS, adr_s(gt * 16 + l16, kk * 32 + g4 * 8));
      MFMA16(acc, kb, qa[kk]);
    }
    sc[gt] = acc;
  }

  // softmax for row h = hb+l16: in-lane over 64 values + 2 shfl (g4 combine)
  float mm = fmaxf(fmaxf(sc[0][0], sc[0][1]), fmaxf(sc[0][2], sc[0][3]));
#pragma unroll
  for (int gt = 1; gt < 16; ++gt) {
    float m4 = fmaxf(fmaxf(sc[gt][0], sc[gt][1]), fmaxf(sc[gt][2], sc[gt][3]));
    mm = fmaxf(mm, m4);
  }
  mm = fmaxf(mm, __shfl_xor(mm, 16, 64));
  mm = fmaxf(mm, __shfl_xor(mm, 32, 64));
  const float mneg = -mm * SCL2;
  float s = 0.f;
#pragma unroll
  for (int gt = 0; gt < 16; ++gt) {
#pragma unroll
    for (int r = 0; r < 4; ++r) {
      float p = exp2f(fmaf(sc[gt][r], SCL2, mneg));
      sc[gt][r] = p;
      s += p;
    }
  }
  s += __shfl_xor(s, 16, 64);
  s += __shfl_xor(s, 32, 64);
  const float rcp = 1.0f / s;

  // normalize + pack to bf16 pairs (f2b only): pk0[gt]=(r0,r1), pk1[gt]=(r2,r3)
  unsigned pk0[16], pk1[16];
#pragma unroll
  for (int gt = 0; gt < 16; ++gt) {
    pk0[gt] = (unsigned)f2b(sc[gt][0] * rcp) | ((unsigned)f2b(sc[gt][1] * rcp) << 16);
    pk1[gt] = (unsigned)f2b(sc[gt][2] * rcp) | ((unsigned)f2b(sc[gt][3] * rcp) << 16);
  }

  // PV: lane-local A-frag (header proof); vb reads identical family to R8
  f32x4 oacc[8];
#pragma unroll
  for (int nt = 0; nt < 8; ++nt) oacc[nt] = (f32x4){0.f, 0.f, 0.f, 0.f};
#pragma unroll
  for (int kks = 0; kks < 8; ++kks) {
    int4v pv = {(int)pk0[2 * kks], (int)pk1[2 * kks],
                (int)pk0[2 * kks + 1], (int)pk1[2 * kks + 1]};
    short8 pa = __builtin_bit_cast(short8, pv);
#pragma unroll
    for (int nt = 0; nt < 8; ++nt) {
      short8 vb = ldsf(VTS, adr_vt(nt * 16 + l16, kks * 32 + g4 * 8));
      MFMA16(oacc[nt], pa, vb);   // D: row g4*4+r -> h-in-16, col l16 -> c (same as R8)
    }
  }

  // att stores (already normalized), R14-validated PS round-trip:
  // ushort stores + ushort readback (TBAA-ordered), full-dword global writes.
#pragma unroll
  for (int ch = 0; ch < 2; ++ch) {
#pragma unroll
    for (int nt4 = 0; nt4 < 4; ++nt4) {
      int nt = ch * 4 + nt4;
#pragma unroll
      for (int r = 0; r < 4; ++r)
        *(unsigned short*)(PS + ps_adr(g4 * 4 + r, nt4 * 16 + l16)) = f2b(oacc[nt][r]);
    }
#pragma unroll
    for (int it = 0; it < 8; ++it) {
      int row = it * 2 + (l >> 5);   // 0..15
      int cd  = l & 31;              // dword within 128B row-half
      unsigned base = (unsigned)(row << 7) +
          (((unsigned)(cd << 2)) ^ (((unsigned)((row ^ (row >> 3)) & 7)) << 4));
      unsigned lo = *(const unsigned short*)(PS + base);
      unsigned hi = *(const unsigned short*)(PS + base + 2);
      ((unsigned*)aws)[(wbase + hb + row) * 64 + ch * 32 + cd] = lo | (hi << 16);
    }
  }
}

// ================= K3: out = relu(wfc . att^T + bfc) — R8-validated ==========
// grid = nbc*64; block tile = 256 n.  LDS: AS [256n][128c] (64K).

__global__ __launch_bounds__(512, 4) void k3_conv(
    const unsigned short* __restrict__ aws, const unsigned short* __restrict__ wb,
    const float* __restrict__ bfc, float* __restrict__ out, int b0)
{
  extern __shared__ char smem[];
  char* AS = smem;

  const int t = threadIdx.x;
  const int wvid = t >> 6, l = t & 63, l16 = l & 15, g4 = l >> 4;
  (void)l;
  const int brel = blockIdx.x >> 6;
  const int n0 = (blockIdx.x & 63) * 256;
  const int b = b0 + brel;

#pragma unroll
  for (int it = 0; it < 8; ++it) {
    int i = it * 512 + t;
    int nn = i >> 4, c16 = i & 15;
    int n = n0 + nn;
    int h = n >> 6, w = n & 63;
    short8 av = *(const short8*)(aws + ((size_t)((brel * 64 + w) * 256 + h)) * 128 + c16 * 8);
    *(short8*)(AS + adr_s(nn, c16 * 8)) = av;
  }
  __syncthreads();

  const int strip = wvid * 16;
  const unsigned short* wfcb = wb + 3 * 16384;
  short8 wf[4];
#pragma unroll
  for (int kk = 0; kk < 4; ++kk)
    wf[kk] = *(const short8*)(wfcb + (strip + l16) * 128 + kk * 32 + g4 * 8);
  float bv4[4];
#pragma unroll
  for (int r = 0; r < 4; ++r) bv4[r] = bfc[strip + g4 * 4 + r];

#pragma unroll
  for (int nt = 0; nt < 16; ++nt) {
    f32x4 acc = {0.f, 0.f, 0.f, 0.f};
#pragma unroll
    for (int kk = 0; kk < 4; ++kk) {
      short8 ab = ldsf(AS, adr_s(nt * 16 + l16, kk * 32 + g4 * 8));
      MFMA16(acc, wf[kk], ab);
    }
#pragma unroll
    for (int r = 0; r < 4; ++r) {
      int o = strip + g4 * 4 + r;
      out[(size_t)(b * 128 + o) * 16384 + n0 + nt * 16 + l16] = fmaxf(acc[r] + bv4[r], 0.f);
    }
  }
}

extern "C" void kernel_launch(void* const* d_in, const int* in_sizes, int n_in,
                              void* d_out, int out_size, void* d_ws, size_t ws_size,
                              hipStream_t stream) {
  const float* rep = (const float*)d_in[0];
  const float* wq  = (const float*)d_in[1];
  const float* bq  = (const float*)d_in[2];
  const float* wk  = (const float*)d_in[3];
  const float* bk  = (const float*)d_in[4];
  const float* wv  = (const float*)d_in[5];
  const float* bv  = (const float*)d_in[6];
  const float* wfc = (const float*)d_in[7];
  const float* bfc = (const float*)d_in[8];
  float* out = (float*)d_out;
  (void)in_sizes; (void)n_in; (void)out_size;

  hipFuncSetAttribute((const void*)k1_qkv,  hipFuncAttributeMaxDynamicSharedMemorySize, 48 * 1024);
  hipFuncSetAttribute((const void*)k2_attn, hipFuncAttributeMaxDynamicSharedMemorySize, 160 * 1024);
  hipFuncSetAttribute((const void*)k3_conv, hipFuncAttributeMaxDynamicSharedMemorySize, 64 * 1024);

  const size_t wb_bytes = 4 * 16384 * 2;          // 128 KB bf16 weights
  const size_t per_b = (size_t)16384 * 128 * 2;   // 4 MiB per array per b
  if (ws_size < wb_bytes + 4 * per_b) return;     // needs >= ~16.1 MB
  size_t nb_max = (ws_size - wb_bytes) / (4 * per_b);
  int nb = (int)(nb_max < 16 ? nb_max : 16);

  char* ws = (char*)d_ws;
  unsigned short* qws = (unsigned short*)(ws);
  unsigned short* kws = (unsigned short*)(ws + (size_t)nb * per_b);
  unsigned short* vws = (unsigned short*)(ws + (size_t)nb * per_b * 2);
  unsigned short* aws = (unsigned short*)(ws + (size_t)nb * per_b * 3);
  unsigned short* wb  = (unsigned short*)(ws + (size_t)nb * per_b * 4);

  k0_wcvt<<<dim3(64), dim3(256), 0, stream>>>(wq, wk, wv, wfc, wb);

  for (int b0 = 0; b0 < 16; b0 += nb) {
    int nbc = (16 - b0) < nb ? (16 - b0) : nb;
    k1_qkv<<<dim3(nbc * 128), dim3(512), 48 * 1024, stream>>>(
        rep, wb, bq, bk, bv, qws, kws, vws, b0);
    k2_attn<<<dim3(nbc * 64), dim3(1024), 160 * 1024, stream>>>(qws, kws, vws, aws);
    k3_conv<<<dim3(nbc * 64), dim3(512), 64 * 1024, stream>>>(aws, wb, bfc, out, b0);
  }
}

// Round 16
// 228.977 us; speedup vs baseline: 1.3703x; 1.0235x over previous
//
#include <hip/hip_runtime.h>

// B=16, C=128, H=256, W=64.  Pipeline (workspace W-MAJOR: [b][w][h][c]):
//  K0: convert wq/wk/wv/wfc fp32->bf16 into ws tail (R8-validated)
//  K1: Q/K/V = relu(Wx+b) -> ws bf16; 16KB half-staged rows (R8-validated)
//  K2: per-(b,w) attention; permuted-K swapped QK^T (R15-validated) with
//      8 waves x 2 m-tiles and K/V fragment REUSE (each LDS b128 read feeds
//      2 MFMAs) -> DS-read instructions halved (k2's measured bottleneck).
//  K3: out = relu(wfc . att^T + bfc) (R8-validated)

typedef __attribute__((ext_vector_type(8))) short short8;
typedef __attribute__((ext_vector_type(4))) float f32x4;
typedef __attribute__((ext_vector_type(4))) int int4v;

#define MFMA16(acc, a, b) (acc) = __builtin_amdgcn_mfma_f32_16x16x32_bf16((a), (b), (acc), 0, 0, 0)

__device__ __forceinline__ unsigned short f2b(float f) {
  unsigned u = __builtin_bit_cast(unsigned, f);
  u = (u + 0x7fffu + ((u >> 16) & 1u)) >> 16;   // RNE
  return (unsigned short)u;
}

// [R][128c] bf16 tile, row-XOR swizzle (verified write-scalar/read-b128 pair)
__device__ __forceinline__ unsigned adr_s(int r, int c) {
  return (unsigned)(((r << 8) + (c << 1)) ^ ((r & 7) << 4));
}
// K1's XS [128j][128c]: stronger row-hash (rows written in stride-4 bursts)
__device__ __forceinline__ unsigned adr_q(int r, int c) {
  return (unsigned)(((r << 8) + (c << 1)) ^ (((r ^ (r >> 3)) & 7) << 4));
}
// V^T tile [128c][256g] (R5-verified double-XOR)
__device__ __forceinline__ unsigned adr_vt(int c, int g) {
  unsigned blk = (unsigned)(((g >> 3) ^ (c & 7) ^ ((c >> 3) & 7)) & 31);
  return (unsigned)((c << 9) + (blk << 4) + ((g & 7) << 1));
}
// per-wave P/att slice [16r][64c] bf16 (2KB), row-hash (R5-verified)
__device__ __forceinline__ unsigned ps_adr(int r, int c) {
  return (unsigned)(((r << 7) + (c << 1)) ^ (((r ^ (r >> 3)) & 7) << 4));
}

__device__ __forceinline__ short8 ldsf(const char* p, unsigned off) {
  return *(const short8*)(p + off);
}

// ================= K0: weight pre-convert fp32 -> bf16 =================
__global__ __launch_bounds__(256) void k0_wcvt(
    const float* __restrict__ wq, const float* __restrict__ wk,
    const float* __restrict__ wv, const float* __restrict__ wfc,
    unsigned short* __restrict__ wb)
{
  int i = blockIdx.x * 256 + threadIdx.x;    // 16384 float4's total
  int mat = i >> 12, off = (i & 4095) * 4;
  const float* src = (mat == 0) ? wq : (mat == 1) ? wk : (mat == 2) ? wv : wfc;
  float4 v = *(const float4*)(src + off);
  uint2 u;
  u.x = (unsigned)f2b(v.x) | ((unsigned)f2b(v.y) << 16);
  u.y = (unsigned)f2b(v.z) | ((unsigned)f2b(v.w) << 16);
  *(uint2*)(wb + mat * 16384 + off) = u;
}

// ================= K1: QKV projection (R8-validated, byte-identical) ==========
// grid = nbc*128; block tile = 128 n (n = h*64+w).
// LDS: XS [128n][128c] @0 (32K), WS half-stage [64n][128c] @32K (16K). 48K.
// Output W-MAJOR: dst[((brel*64+w)*256 + h)*128 + c].

__device__ __forceinline__ void k1_one(const unsigned short* wmat, const float* bias,
    unsigned short* dst, const char* XS, char* WS,
    int brel, int n0, int wvid, int l, int l16, int g4) {
  const int strip = wvid * 16;
  short8 wf[4];
#pragma unroll
  for (int kk = 0; kk < 4; ++kk)
    wf[kk] = *(const short8*)(wmat + (strip + l16) * 128 + kk * 32 + g4 * 8);
  float bv4[4];
#pragma unroll
  for (int r = 0; r < 4; ++r) bv4[r] = bias[strip + g4 * 4 + r];

  f32x4 acc[8];
#pragma unroll
  for (int nt = 0; nt < 8; ++nt) acc[nt] = (f32x4){0.f, 0.f, 0.f, 0.f};
#pragma unroll
  for (int nt = 0; nt < 8; ++nt) {
#pragma unroll
    for (int kk = 0; kk < 4; ++kk) {
      short8 xb = ldsf(XS, adr_q(nt * 16 + l16, kk * 32 + g4 * 8));
      MFMA16(acc[nt], wf[kk], xb);   // D[o][n']: col=l16 -> n', row=g4*4+r -> o
    }
  }
  // two 64-row halves through the 16K WS
#pragma unroll
  for (int hf = 0; hf < 2; ++hf) {
    __syncthreads();   // WS free (previous readback complete)
#pragma unroll
    for (int nt4 = 0; nt4 < 4; ++nt4) {
      int nt = hf * 4 + nt4;
      float y0 = fmaxf(acc[nt][0] + bv4[0], 0.f);
      float y1 = fmaxf(acc[nt][1] + bv4[1], 0.f);
      float y2 = fmaxf(acc[nt][2] + bv4[2], 0.f);
      float y3 = fmaxf(acc[nt][3] + bv4[3], 0.f);
      uint2 u;
      u.x = (unsigned)f2b(y0) | ((unsigned)f2b(y1) << 16);
      u.y = (unsigned)f2b(y2) | ((unsigned)f2b(y3) << 16);
      int row = nt4 * 16 + l16;                       // 0..63
      unsigned cb = (unsigned)(wvid * 32 + g4 * 8);
      *(uint2*)(WS + (unsigned)(row << 8) + (cb ^ ((unsigned)(row & 7) << 4))) = u;
    }
    __syncthreads();
    // readback full 256B rows -> w-major global rows
#pragma unroll
    for (int it = 0; it < 8; ++it) {
      int row = it * 8 + wvid;                        // 0..63
      unsigned u = *(const unsigned*)(WS + (unsigned)(row << 8) +
                                     (((unsigned)(l << 2)) ^ ((unsigned)(row & 7) << 4)));
      int n = n0 + hf * 64 + row;
      int h = n >> 6, w = n & 63;
      ((unsigned*)dst)[(size_t)((brel * 64 + w) * 256 + h) * 64 + l] = u;
    }
  }
}

__global__ __launch_bounds__(512, 4) void k1_qkv(
    const float* __restrict__ rep, const unsigned short* __restrict__ wb,
    const float* __restrict__ bq, const float* __restrict__ bk,
    const float* __restrict__ bv,
    unsigned short* __restrict__ qo, unsigned short* __restrict__ ko,
    unsigned short* __restrict__ vo, int b0)
{
  extern __shared__ char smem[];
  char* XS = smem;               // 32K
  char* WS = smem + (32 << 10);  // 16K

  const int t = threadIdx.x;
  const int wvid = t >> 6, l = t & 63, l16 = l & 15, g4 = l >> 4;
  const int brel = blockIdx.x >> 7;
  const int n0 = (blockIdx.x & 127) * 128;
  const int b = b0 + brel;

#pragma unroll
  for (int it = 0; it < 8; ++it) {
    int i = it * 512 + t;
    int c = i >> 5, j4 = i & 31;
    float4 xv = *(const float4*)(rep + (size_t)(b * 128 + c) * 16384 + n0 + j4 * 4);
    float vv[4] = {xv.x, xv.y, xv.z, xv.w};
#pragma unroll
    for (int r = 0; r < 4; ++r)
      *(unsigned short*)(XS + adr_q(j4 * 4 + r, c)) = f2b(vv[r]);
  }
  __syncthreads();

  k1_one(wb,         bq, qo, XS, WS, brel, n0, wvid, l, l16, g4);
  k1_one(wb + 16384, bk, ko, XS, WS, brel, n0, wvid, l, l16, g4);
  k1_one(wb + 32768, bv, vo, XS, WS, brel, n0, wvid, l, l16, g4);
}

// ================= K2: attention per (b,w), permuted-K, frag-reuse ==========
// 512 thr (8 waves), wave owns TWO 16-row m-tiles (hb0=wvid*32, hb1=+16).
// LDS: KS 64K @0, VTS 64K @64K, PS att-slices @128K (8 x 2K). Total 144K.
// Each kb/vb LDS fragment is read ONCE and feeds 2 MFMAs (m0, m1):
// halves ds_read_b128 count — k2's measured bottleneck (~40us of 100us).
// Per-m math identical to R15 (validated): K row g at position
// p(g)=32(g>>5)|16((g>>2)&1)|4((g>>3)&3)|(g&3); swapped MFMA(K,Q) leaves a
// full P-row per lane; PV A-frag lane-local.

__global__ __launch_bounds__(512, 2) void k2_attn(
    const unsigned short* __restrict__ qws, const unsigned short* __restrict__ kws,
    const unsigned short* __restrict__ vws, unsigned short* __restrict__ aws)
{
  extern __shared__ char smem[];
  char* KS  = smem;
  char* VTS = smem + (64 << 10);

  const int t = threadIdx.x;
  const int wvid = t >> 6, l = t & 63, l16 = l & 15, g4 = l >> 4;
  char* PS = smem + (128 << 10) + (wvid << 11);

  const int brel = blockIdx.x >> 6;
  const int w = blockIdx.x & 63;
  const size_t wbase = (size_t)((brel * 64 + w)) * 256;   // row index of (b,w,h=0)

  const int hb0 = wvid * 32;
  const int hb1 = wvid * 32 + 16;

  // q rows for both m-tiles (contiguous reads)
  short8 qa0[4], qa1[4];
#pragma unroll
  for (int kk = 0; kk < 4; ++kk) {
    qa0[kk] = *(const short8*)(qws + (wbase + hb0 + l16) * 128 + kk * 32 + g4 * 8);
    qa1[kk] = *(const short8*)(qws + (wbase + hb1 + l16) * 128 + kk * 32 + g4 * 8);
  }

  // stage K rows [g][c] at permuted position p(g) — contiguous global reads
#pragma unroll
  for (int it = 0; it < 8; ++it) {
    int i = it * 512 + t;
    int g = i >> 4, c16 = i & 15;
    int gp = (g & ~31) | ((g & 4) << 2) | ((g >> 1) & 12) | (g & 3);
    short8 kv = *(const short8*)(kws + (wbase + g) * 128 + c16 * 8);
    *(short8*)(KS + adr_s(gp, c16 * 8)) = kv;
  }
  // stage V^T [c][g] — contiguous reads, scalar swizzled writes (natural g)
#pragma unroll
  for (int it = 0; it < 8; ++it) {
    int i = it * 512 + t;
    int g = i >> 4, c16 = i & 15;
    short8 vv = *(const short8*)(vws + (wbase + g) * 128 + c16 * 8);
#pragma unroll
    for (int j = 0; j < 8; ++j)
      *(unsigned short*)(VTS + adr_vt(c16 * 8 + j, g)) = (unsigned short)vv[j];
  }
  __syncthreads();

  const float SCL2 = 0.08838834764831845f * 1.4426950408889634f; // rsqrt(128)*log2e

  // swapped scores, frag-reuse: each kb read feeds both m-tiles
  f32x4 sc0[16], sc1[16];
#pragma unroll
  for (int gt = 0; gt < 16; ++gt) {
    f32x4 a0 = {0.f, 0.f, 0.f, 0.f};
    f32x4 a1 = {0.f, 0.f, 0.f, 0.f};
#pragma unroll
    for (int kk = 0; kk < 4; ++kk) {
      short8 kb = ldsf(KS, adr_s(gt * 16 + l16, kk * 32 + g4 * 8));
      MFMA16(a0, kb, qa0[kk]);
      MFMA16(a1, kb, qa1[kk]);
    }
    sc0[gt] = a0;
    sc1[gt] = a1;
  }

  // softmax m0 (row h = hb0+l16): in-lane + 2 shfl; pack to pk (frees sc0)
  unsigned pk0a[16], pk1a[16];
  {
    float mm = fmaxf(fmaxf(sc0[0][0], sc0[0][1]), fmaxf(sc0[0][2], sc0[0][3]));
#pragma unroll
    for (int gt = 1; gt < 16; ++gt) {
      float m4 = fmaxf(fmaxf(sc0[gt][0], sc0[gt][1]), fmaxf(sc0[gt][2], sc0[gt][3]));
      mm = fmaxf(mm, m4);
    }
    mm = fmaxf(mm, __shfl_xor(mm, 16, 64));
    mm = fmaxf(mm, __shfl_xor(mm, 32, 64));
    const float mneg = -mm * SCL2;
    float s = 0.f;
#pragma unroll
    for (int gt = 0; gt < 16; ++gt) {
#pragma unroll
      for (int r = 0; r < 4; ++r) {
        float p = exp2f(fmaf(sc0[gt][r], SCL2, mneg));
        sc0[gt][r] = p;
        s += p;
      }
    }
    s += __shfl_xor(s, 16, 64);
    s += __shfl_xor(s, 32, 64);
    const float rcp = 1.0f / s;
#pragma unroll
    for (int gt = 0; gt < 16; ++gt) {
      pk0a[gt] = (unsigned)f2b(sc0[gt][0] * rcp) | ((unsigned)f2b(sc0[gt][1] * rcp) << 16);
      pk1a[gt] = (unsigned)f2b(sc0[gt][2] * rcp) | ((unsigned)f2b(sc0[gt][3] * rcp) << 16);
    }
  }
  // softmax m1
  unsigned pk0b[16], pk1b[16];
  {
    float mm = fmaxf(fmaxf(sc1[0][0], sc1[0][1]), fmaxf(sc1[0][2], sc1[0][3]));
#pragma unroll
    for (int gt = 1; gt < 16; ++gt) {
      float m4 = fmaxf(fmaxf(sc1[gt][0], sc1[gt][1]), fmaxf(sc1[gt][2], sc1[gt][3]));
      mm = fmaxf(mm, m4);
    }
    mm = fmaxf(mm, __shfl_xor(mm, 16, 64));
    mm = fmaxf(mm, __shfl_xor(mm, 32, 64));
    const float mneg = -mm * SCL2;
    float s = 0.f;
#pragma unroll
    for (int gt = 0; gt < 16; ++gt) {
#pragma unroll
      for (int r = 0; r < 4; ++r) {
        float p = exp2f(fmaf(sc1[gt][r], SCL2, mneg));
        sc1[gt][r] = p;
        s += p;
      }
    }
    s += __shfl_xor(s, 16, 64);
    s += __shfl_xor(s, 32, 64);
    const float rcp = 1.0f / s;
#pragma unroll
    for (int gt = 0; gt < 16; ++gt) {
      pk0b[gt] = (unsigned)f2b(sc1[gt][0] * rcp) | ((unsigned)f2b(sc1[gt][1] * rcp) << 16);
      pk1b[gt] = (unsigned)f2b(sc1[gt][2] * rcp) | ((unsigned)f2b(sc1[gt][3] * rcp) << 16);
    }
  }

  // PV, frag-reuse: each vb read feeds both m-tiles (lane-local A-frags)
  f32x4 oacc0[8], oacc1[8];
#pragma unroll
  for (int nt = 0; nt < 8; ++nt) {
    oacc0[nt] = (f32x4){0.f, 0.f, 0.f, 0.f};
    oacc1[nt] = (f32x4){0.f, 0.f, 0.f, 0.f};
  }
#pragma unroll
  for (int kks = 0; kks < 8; ++kks) {
    int4v pv0 = {(int)pk0a[2 * kks], (int)pk1a[2 * kks],
                 (int)pk0a[2 * kks + 1], (int)pk1a[2 * kks + 1]};
    int4v pv1 = {(int)pk0b[2 * kks], (int)pk1b[2 * kks],
                 (int)pk0b[2 * kks + 1], (int)pk1b[2 * kks + 1]};
    short8 pa0 = __builtin_bit_cast(short8, pv0);
    short8 pa1 = __builtin_bit_cast(short8, pv1);
#pragma unroll
    for (int nt = 0; nt < 8; ++nt) {
      short8 vb = ldsf(VTS, adr_vt(nt * 16 + l16, kks * 32 + g4 * 8));
      MFMA16(oacc0[nt], pa0, vb);
      MFMA16(oacc1[nt], pa1, vb);
    }
  }

  // att stores (normalized), R14-validated PS round-trip, once per m-tile
#pragma unroll
  for (int m = 0; m < 2; ++m) {
    const int hb = (m == 0) ? hb0 : hb1;
#pragma unroll
    for (int ch = 0; ch < 2; ++ch) {
#pragma unroll
      for (int nt4 = 0; nt4 < 4; ++nt4) {
        int nt = ch * 4 + nt4;
        f32x4 ov = (m == 0) ? oacc0[nt] : oacc1[nt];
#pragma unroll
        for (int r = 0; r < 4; ++r)
          *(unsigned short*)(PS + ps_adr(g4 * 4 + r, nt4 * 16 + l16)) = f2b(ov[r]);
      }
#pragma unroll
      for (int it = 0; it < 8; ++it) {
        int row = it * 2 + (l >> 5);   // 0..15
        int cd  = l & 31;              // dword within 128B row-half
        unsigned base = (unsigned)(row << 7) +
            (((unsigned)(cd << 2)) ^ (((unsigned)((row ^ (row >> 3)) & 7)) << 4));
        unsigned lo = *(const unsigned short*)(PS + base);
        unsigned hi = *(const unsigned short*)(PS + base + 2);
        ((unsigned*)aws)[(wbase + hb + row) * 64 + ch * 32 + cd] = lo | (hi << 16);
      }
    }
  }
}

// ================= K3: out = relu(wfc . att^T + bfc) — R8-validated ==========
// grid = nbc*64; block tile = 256 n.  LDS: AS [256n][128c] (64K).

__global__ __launch_bounds__(512, 4) void k3_conv(
    const unsigned short* __restrict__ aws, const unsigned short* __restrict__ wb,
    const float* __restrict__ bfc, float* __restrict__ out, int b0)
{
  extern __shared__ char smem[];
  char* AS = smem;

  const int t = threadIdx.x;
  const int wvid = t >> 6, l = t & 63, l16 = l & 15, g4 = l >> 4;
  (void)l;
  const int brel = blockIdx.x >> 6;
  const int n0 = (blockIdx.x & 63) * 256;
  const int b = b0 + brel;

#pragma unroll
  for (int it = 0; it < 8; ++it) {
    int i = it * 512 + t;
    int nn = i >> 4, c16 = i & 15;
    int n = n0 + nn;
    int h = n >> 6, w = n & 63;
    short8 av = *(const short8*)(aws + ((size_t)((brel * 64 + w) * 256 + h)) * 128 + c16 * 8);
    *(short8*)(AS + adr_s(nn, c16 * 8)) = av;
  }
  __syncthreads();

  const int strip = wvid * 16;
  const unsigned short* wfcb = wb + 3 * 16384;
  short8 wf[4];
#pragma unroll
  for (int kk = 0; kk < 4; ++kk)
    wf[kk] = *(const short8*)(wfcb + (strip + l16) * 128 + kk * 32 + g4 * 8);
  float bv4[4];
#pragma unroll
  for (int r = 0; r < 4; ++r) bv4[r] = bfc[strip + g4 * 4 + r];

#pragma unroll
  for (int nt = 0; nt < 16; ++nt) {
    f32x4 acc = {0.f, 0.f, 0.f, 0.f};
#pragma unroll
    for (int kk = 0; kk < 4; ++kk) {
      short8 ab = ldsf(AS, adr_s(nt * 16 + l16, kk * 32 + g4 * 8));
      MFMA16(acc, wf[kk], ab);
    }
#pragma unroll
    for (int r = 0; r < 4; ++r) {
      int o = strip + g4 * 4 + r;
      out[(size_t)(b * 128 + o) * 16384 + n0 + nt * 16 + l16] = fmaxf(acc[r] + bv4[r], 0.f);
    }
  }
}

extern "C" void kernel_launch(void* const* d_in, const int* in_sizes, int n_in,
                              void* d_out, int out_size, void* d_ws, size_t ws_size,
                              hipStream_t stream) {
  const float* rep = (const float*)d_in[0];
  const float* wq  = (const float*)d_in[1];
  const float* bq  = (const float*)d_in[2];
  const float* wk  = (const float*)d_in[3];
  const float* bk  = (const float*)d_in[4];
  const float* wv  = (const float*)d_in[5];
  const float* bv  = (const float*)d_in[6];
  const float* wfc = (const float*)d_in[7];
  const float* bfc = (const float*)d_in[8];
  float* out = (float*)d_out;
  (void)in_sizes; (void)n_in; (void)out_size;

  hipFuncSetAttribute((const void*)k1_qkv,  hipFuncAttributeMaxDynamicSharedMemorySize, 48 * 1024);
  hipFuncSetAttribute((const void*)k2_attn, hipFuncAttributeMaxDynamicSharedMemorySize, 144 * 1024);
  hipFuncSetAttribute((const void*)k3_conv, hipFuncAttributeMaxDynamicSharedMemorySize, 64 * 1024);

  const size_t wb_bytes = 4 * 16384 * 2;          // 128 KB bf16 weights
  const size_t per_b = (size_t)16384 * 128 * 2;   // 4 MiB per array per b
  if (ws_size < wb_bytes + 4 * per_b) return;     // needs >= ~16.1 MB
  size_t nb_max = (ws_size - wb_bytes) / (4 * per_b);
  int nb = (int)(nb_max < 16 ? nb_max : 16);

  char* ws = (char*)d_ws;
  unsigned short* qws = (unsigned short*)(ws);
  unsigned short* kws = (unsigned short*)(ws + (size_t)nb * per_b);
  unsigned short* vws = (unsigned short*)(ws + (size_t)nb * per_b * 2);
  unsigned short* aws = (unsigned short*)(ws + (size_t)nb * per_b * 3);
  unsigned short* wb  = (unsigned short*)(ws + (size_t)nb * per_b * 4);

  k0_wcvt<<<dim3(64), dim3(256), 0, stream>>>(wq, wk, wv, wfc, wb);

  for (int b0 = 0; b0 < 16; b0 += nb) {
    int nbc = (16 - b0) < nb ? (16 - b0) : nb;
    k1_qkv<<<dim3(nbc * 128), dim3(512), 48 * 1024, stream>>>(
        rep, wb, bq, bk, bv, qws, kws, vws, b0);
    k2_attn<<<dim3(nbc * 64), dim3(512), 144 * 1024, stream>>>(qws, kws, vws, aws);
    k3_conv<<<dim3(nbc * 64), dim3(512), 64 * 1024, stream>>>(aws, wb, bfc, out, b0);
  }
}

// Round 17
// 228.519 us; speedup vs baseline: 1.3731x; 1.0020x over previous
//
#include <hip/hip_runtime.h>

// B=16, C=128, H=256, W=64.  Pipeline (workspace W-MAJOR: [b][w][h][c]):
//  K0: convert wq/wk/wv/wfc fp32->bf16 into ws tail (R8-validated)
//  K1: Q/K/V = relu(Wx+b) -> ws bf16; 8KB QUARTER-staged rows (R12-validated
//      text, WITHOUT the weight-prefetch that caused R12's spills).
//      40KB LDS -> 4 blocks/CU (was 3).
//  K2: per-(b,w) attention; permuted-K swapped QK^T, 8 waves x 2 m-tiles,
//      K/V fragment reuse (R16-validated, byte-identical)
//  K3: out = relu(wfc . att^T + bfc) (R8-validated)

typedef __attribute__((ext_vector_type(8))) short short8;
typedef __attribute__((ext_vector_type(4))) float f32x4;
typedef __attribute__((ext_vector_type(4))) int int4v;

#define MFMA16(acc, a, b) (acc) = __builtin_amdgcn_mfma_f32_16x16x32_bf16((a), (b), (acc), 0, 0, 0)

__device__ __forceinline__ unsigned short f2b(float f) {
  unsigned u = __builtin_bit_cast(unsigned, f);
  u = (u + 0x7fffu + ((u >> 16) & 1u)) >> 16;   // RNE
  return (unsigned short)u;
}

// [R][128c] bf16 tile, row-XOR swizzle (verified write-scalar/read-b128 pair)
__device__ __forceinline__ unsigned adr_s(int r, int c) {
  return (unsigned)(((r << 8) + (c << 1)) ^ ((r & 7) << 4));
}
// K1's XS [128j][128c]: stronger row-hash (rows written in stride-4 bursts)
__device__ __forceinline__ unsigned adr_q(int r, int c) {
  return (unsigned)(((r << 8) + (c << 1)) ^ (((r ^ (r >> 3)) & 7) << 4));
}
// V^T tile [128c][256g] (R5-verified double-XOR)
__device__ __forceinline__ unsigned adr_vt(int c, int g) {
  unsigned blk = (unsigned)(((g >> 3) ^ (c & 7) ^ ((c >> 3) & 7)) & 31);
  return (unsigned)((c << 9) + (blk << 4) + ((g & 7) << 1));
}
// per-wave P/att slice [16r][64c] bf16 (2KB), row-hash (R5-verified)
__device__ __forceinline__ unsigned ps_adr(int r, int c) {
  return (unsigned)(((r << 7) + (c << 1)) ^ (((r ^ (r >> 3)) & 7) << 4));
}

__device__ __forceinline__ short8 ldsf(const char* p, unsigned off) {
  return *(const short8*)(p + off);
}

// ================= K0: weight pre-convert fp32 -> bf16 =================
__global__ __launch_bounds__(256) void k0_wcvt(
    const float* __restrict__ wq, const float* __restrict__ wk,
    const float* __restrict__ wv, const float* __restrict__ wfc,
    unsigned short* __restrict__ wb)
{
  int i = blockIdx.x * 256 + threadIdx.x;    // 16384 float4's total
  int mat = i >> 12, off = (i & 4095) * 4;
  const float* src = (mat == 0) ? wq : (mat == 1) ? wk : (mat == 2) ? wv : wfc;
  float4 v = *(const float4*)(src + off);
  uint2 u;
  u.x = (unsigned)f2b(v.x) | ((unsigned)f2b(v.y) << 16);
  u.y = (unsigned)f2b(v.z) | ((unsigned)f2b(v.w) << 16);
  *(uint2*)(wb + mat * 16384 + off) = u;
}

// ================= K1: QKV projection =================
// grid = nbc*128; block tile = 128 n (n = h*64+w).
// LDS: XS [128n][128c] @0 (32K), WS quarter-stage [32n][128c] @32K (8K). 40K.
// Output W-MAJOR: dst[((brel*64+w)*256 + h)*128 + c].

__device__ __forceinline__ void k1_one(const unsigned short* wmat, const float* bias,
    unsigned short* dst, const char* XS, char* WS,
    int brel, int n0, int wvid, int l, int l16, int g4) {
  const int strip = wvid * 16;
  short8 wf[4];
#pragma unroll
  for (int kk = 0; kk < 4; ++kk)
    wf[kk] = *(const short8*)(wmat + (strip + l16) * 128 + kk * 32 + g4 * 8);
  float bv4[4];
#pragma unroll
  for (int r = 0; r < 4; ++r) bv4[r] = bias[strip + g4 * 4 + r];

  f32x4 acc[8];
#pragma unroll
  for (int nt = 0; nt < 8; ++nt) acc[nt] = (f32x4){0.f, 0.f, 0.f, 0.f};
#pragma unroll
  for (int nt = 0; nt < 8; ++nt) {
#pragma unroll
    for (int kk = 0; kk < 4; ++kk) {
      short8 xb = ldsf(XS, adr_q(nt * 16 + l16, kk * 32 + g4 * 8));
      MFMA16(acc[nt], wf[kk], xb);   // D[o][n']: col=l16 -> n', row=g4*4+r -> o
    }
  }
  // four 32-row quarters through the 8K WS (R12-validated text)
#pragma unroll
  for (int qt = 0; qt < 4; ++qt) {
    __syncthreads();   // WS free (previous readback complete)
#pragma unroll
    for (int nt2 = 0; nt2 < 2; ++nt2) {
      int nt = qt * 2 + nt2;
      float y0 = fmaxf(acc[nt][0] + bv4[0], 0.f);
      float y1 = fmaxf(acc[nt][1] + bv4[1], 0.f);
      float y2 = fmaxf(acc[nt][2] + bv4[2], 0.f);
      float y3 = fmaxf(acc[nt][3] + bv4[3], 0.f);
      uint2 u;
      u.x = (unsigned)f2b(y0) | ((unsigned)f2b(y1) << 16);
      u.y = (unsigned)f2b(y2) | ((unsigned)f2b(y3) << 16);
      int row = nt2 * 16 + l16;                       // 0..31
      unsigned cb = (unsigned)(wvid * 32 + g4 * 8);
      *(uint2*)(WS + (unsigned)(row << 8) + (cb ^ ((unsigned)(row & 7) << 4))) = u;
    }
    __syncthreads();
    // readback full 256B rows -> w-major global rows
#pragma unroll
    for (int it = 0; it < 4; ++it) {
      int row = it * 8 + wvid;                        // 0..31
      unsigned u = *(const unsigned*)(WS + (unsigned)(row << 8) +
                                     (((unsigned)(l << 2)) ^ ((unsigned)(row & 7) << 4)));
      int n = n0 + qt * 32 + row;
      int h = n >> 6, w = n & 63;
      ((unsigned*)dst)[(size_t)((brel * 64 + w) * 256 + h) * 64 + l] = u;
    }
  }
}

__global__ __launch_bounds__(512, 4) void k1_qkv(
    const float* __restrict__ rep, const unsigned short* __restrict__ wb,
    const float* __restrict__ bq, const float* __restrict__ bk,
    const float* __restrict__ bv,
    unsigned short* __restrict__ qo, unsigned short* __restrict__ ko,
    unsigned short* __restrict__ vo, int b0)
{
  extern __shared__ char smem[];
  char* XS = smem;               // 32K
  char* WS = smem + (32 << 10);  // 8K

  const int t = threadIdx.x;
  const int wvid = t >> 6, l = t & 63, l16 = l & 15, g4 = l >> 4;
  const int brel = blockIdx.x >> 7;
  const int n0 = (blockIdx.x & 127) * 128;
  const int b = b0 + brel;

#pragma unroll
  for (int it = 0; it < 8; ++it) {
    int i = it * 512 + t;
    int c = i >> 5, j4 = i & 31;
    float4 xv = *(const float4*)(rep + (size_t)(b * 128 + c) * 16384 + n0 + j4 * 4);
    float vv[4] = {xv.x, xv.y, xv.z, xv.w};
#pragma unroll
    for (int r = 0; r < 4; ++r)
      *(unsigned short*)(XS + adr_q(j4 * 4 + r, c)) = f2b(vv[r]);
  }
  __syncthreads();

  k1_one(wb,         bq, qo, XS, WS, brel, n0, wvid, l, l16, g4);
  k1_one(wb + 16384, bk, ko, XS, WS, brel, n0, wvid, l, l16, g4);
  k1_one(wb + 32768, bv, vo, XS, WS, brel, n0, wvid, l, l16, g4);
}

// ================= K2: attention per (b,w), permuted-K, frag-reuse ==========
// (R16-validated, byte-identical.)
// 512 thr (8 waves), wave owns TWO 16-row m-tiles (hb0=wvid*32, hb1=+16).
// LDS: KS 64K @0, VTS 64K @64K, PS att-slices @128K (8 x 2K). Total 144K.

__global__ __launch_bounds__(512, 2) void k2_attn(
    const unsigned short* __restrict__ qws, const unsigned short* __restrict__ kws,
    const unsigned short* __restrict__ vws, unsigned short* __restrict__ aws)
{
  extern __shared__ char smem[];
  char* KS  = smem;
  char* VTS = smem + (64 << 10);

  const int t = threadIdx.x;
  const int wvid = t >> 6, l = t & 63, l16 = l & 15, g4 = l >> 4;
  char* PS = smem + (128 << 10) + (wvid << 11);

  const int brel = blockIdx.x >> 6;
  const int w = blockIdx.x & 63;
  const size_t wbase = (size_t)((brel * 64 + w)) * 256;   // row index of (b,w,h=0)

  const int hb0 = wvid * 32;
  const int hb1 = wvid * 32 + 16;

  // q rows for both m-tiles (contiguous reads)
  short8 qa0[4], qa1[4];
#pragma unroll
  for (int kk = 0; kk < 4; ++kk) {
    qa0[kk] = *(const short8*)(qws + (wbase + hb0 + l16) * 128 + kk * 32 + g4 * 8);
    qa1[kk] = *(const short8*)(qws + (wbase + hb1 + l16) * 128 + kk * 32 + g4 * 8);
  }

  // stage K rows [g][c] at permuted position p(g) — contiguous global reads
#pragma unroll
  for (int it = 0; it < 8; ++it) {
    int i = it * 512 + t;
    int g = i >> 4, c16 = i & 15;
    int gp = (g & ~31) | ((g & 4) << 2) | ((g >> 1) & 12) | (g & 3);
    short8 kv = *(const short8*)(kws + (wbase + g) * 128 + c16 * 8);
    *(short8*)(KS + adr_s(gp, c16 * 8)) = kv;
  }
  // stage V^T [c][g] — contiguous reads, scalar swizzled writes (natural g)
#pragma unroll
  for (int it = 0; it < 8; ++it) {
    int i = it * 512 + t;
    int g = i >> 4, c16 = i & 15;
    short8 vv = *(const short8*)(vws + (wbase + g) * 128 + c16 * 8);
#pragma unroll
    for (int j = 0; j < 8; ++j)
      *(unsigned short*)(VTS + adr_vt(c16 * 8 + j, g)) = (unsigned short)vv[j];
  }
  __syncthreads();

  const float SCL2 = 0.08838834764831845f * 1.4426950408889634f; // rsqrt(128)*log2e

  // swapped scores, frag-reuse: each kb read feeds both m-tiles
  f32x4 sc0[16], sc1[16];
#pragma unroll
  for (int gt = 0; gt < 16; ++gt) {
    f32x4 a0 = {0.f, 0.f, 0.f, 0.f};
    f32x4 a1 = {0.f, 0.f, 0.f, 0.f};
#pragma unroll
    for (int kk = 0; kk < 4; ++kk) {
      short8 kb = ldsf(KS, adr_s(gt * 16 + l16, kk * 32 + g4 * 8));
      MFMA16(a0, kb, qa0[kk]);
      MFMA16(a1, kb, qa1[kk]);
    }
    sc0[gt] = a0;
    sc1[gt] = a1;
  }

  // softmax m0 (row h = hb0+l16): in-lane + 2 shfl; pack to pk (frees sc0)
  unsigned pk0a[16], pk1a[16];
  {
    float mm = fmaxf(fmaxf(sc0[0][0], sc0[0][1]), fmaxf(sc0[0][2], sc0[0][3]));
#pragma unroll
    for (int gt = 1; gt < 16; ++gt) {
      float m4 = fmaxf(fmaxf(sc0[gt][0], sc0[gt][1]), fmaxf(sc0[gt][2], sc0[gt][3]));
      mm = fmaxf(mm, m4);
    }
    mm = fmaxf(mm, __shfl_xor(mm, 16, 64));
    mm = fmaxf(mm, __shfl_xor(mm, 32, 64));
    const float mneg = -mm * SCL2;
    float s = 0.f;
#pragma unroll
    for (int gt = 0; gt < 16; ++gt) {
#pragma unroll
      for (int r = 0; r < 4; ++r) {
        float p = exp2f(fmaf(sc0[gt][r], SCL2, mneg));
        sc0[gt][r] = p;
        s += p;
      }
    }
    s += __shfl_xor(s, 16, 64);
    s += __shfl_xor(s, 32, 64);
    const float rcp = 1.0f / s;
#pragma unroll
    for (int gt = 0; gt < 16; ++gt) {
      pk0a[gt] = (unsigned)f2b(sc0[gt][0] * rcp) | ((unsigned)f2b(sc0[gt][1] * rcp) << 16);
      pk1a[gt] = (unsigned)f2b(sc0[gt][2] * rcp) | ((unsigned)f2b(sc0[gt][3] * rcp) << 16);
    }
  }
  // softmax m1
  unsigned pk0b[16], pk1b[16];
  {
    float mm = fmaxf(fmaxf(sc1[0][0], sc1[0][1]), fmaxf(sc1[0][2], sc1[0][3]));
#pragma unroll
    for (int gt = 1; gt < 16; ++gt) {
      float m4 = fmaxf(fmaxf(sc1[gt][0], sc1[gt][1]), fmaxf(sc1[gt][2], sc1[gt][3]));
      mm = fmaxf(mm, m4);
    }
    mm = fmaxf(mm, __shfl_xor(mm, 16, 64));
    mm = fmaxf(mm, __shfl_xor(mm, 32, 64));
    const float mneg = -mm * SCL2;
    float s = 0.f;
#pragma unroll
    for (int gt = 0; gt < 16; ++gt) {
#pragma unroll
      for (int r = 0; r < 4; ++r) {
        float p = exp2f(fmaf(sc1[gt][r], SCL2, mneg));
        sc1[gt][r] = p;
        s += p;
      }
    }
    s += __shfl_xor(s, 16, 64);
    s += __shfl_xor(s, 32, 64);
    const float rcp = 1.0f / s;
#pragma unroll
    for (int gt = 0; gt < 16; ++gt) {
      pk0b[gt] = (unsigned)f2b(sc1[gt][0] * rcp) | ((unsigned)f2b(sc1[gt][1] * rcp) << 16);
      pk1b[gt] = (unsigned)f2b(sc1[gt][2] * rcp) | ((unsigned)f2b(sc1[gt][3] * rcp) << 16);
    }
  }

  // PV, frag-reuse: each vb read feeds both m-tiles (lane-local A-frags)
  f32x4 oacc0[8], oacc1[8];
#pragma unroll
  for (int nt = 0; nt < 8; ++nt) {
    oacc0[nt] = (f32x4){0.f, 0.f, 0.f, 0.f};
    oacc1[nt] = (f32x4){0.f, 0.f, 0.f, 0.f};
  }
#pragma unroll
  for (int kks = 0; kks < 8; ++kks) {
    int4v pv0 = {(int)pk0a[2 * kks], (int)pk1a[2 * kks],
                 (int)pk0a[2 * kks + 1], (int)pk1a[2 * kks + 1]};
    int4v pv1 = {(int)pk0b[2 * kks], (int)pk1b[2 * kks],
                 (int)pk0b[2 * kks + 1], (int)pk1b[2 * kks + 1]};
    short8 pa0 = __builtin_bit_cast(short8, pv0);
    short8 pa1 = __builtin_bit_cast(short8, pv1);
#pragma unroll
    for (int nt = 0; nt < 8; ++nt) {
      short8 vb = ldsf(VTS, adr_vt(nt * 16 + l16, kks * 32 + g4 * 8));
      MFMA16(oacc0[nt], pa0, vb);
      MFMA16(oacc1[nt], pa1, vb);
    }
  }

  // att stores (normalized), R14-validated PS round-trip, once per m-tile
#pragma unroll
  for (int m = 0; m < 2; ++m) {
    const int hb = (m == 0) ? hb0 : hb1;
#pragma unroll
    for (int ch = 0; ch < 2; ++ch) {
#pragma unroll
      for (int nt4 = 0; nt4 < 4; ++nt4) {
        int nt = ch * 4 + nt4;
        f32x4 ov = (m == 0) ? oacc0[nt] : oacc1[nt];
#pragma unroll
        for (int r = 0; r < 4; ++r)
          *(unsigned short*)(PS + ps_adr(g4 * 4 + r, nt4 * 16 + l16)) = f2b(ov[r]);
      }
#pragma unroll
      for (int it = 0; it < 8; ++it) {
        int row = it * 2 + (l >> 5);   // 0..15
        int cd  = l & 31;              // dword within 128B row-half
        unsigned base = (unsigned)(row << 7) +
            (((unsigned)(cd << 2)) ^ (((unsigned)((row ^ (row >> 3)) & 7)) << 4));
        unsigned lo = *(const unsigned short*)(PS + base);
        unsigned hi = *(const unsigned short*)(PS + base + 2);
        ((unsigned*)aws)[(wbase + hb + row) * 64 + ch * 32 + cd] = lo | (hi << 16);
      }
    }
  }
}

// ================= K3: out = relu(wfc . att^T + bfc) — R8-validated ==========
// grid = nbc*64; block tile = 256 n.  LDS: AS [256n][128c] (64K).

__global__ __launch_bounds__(512, 4) void k3_conv(
    const unsigned short* __restrict__ aws, const unsigned short* __restrict__ wb,
    const float* __restrict__ bfc, float* __restrict__ out, int b0)
{
  extern __shared__ char smem[];
  char* AS = smem;

  const int t = threadIdx.x;
  const int wvid = t >> 6, l = t & 63, l16 = l & 15, g4 = l >> 4;
  (void)l;
  const int brel = blockIdx.x >> 6;
  const int n0 = (blockIdx.x & 63) * 256;
  const int b = b0 + brel;

#pragma unroll
  for (int it = 0; it < 8; ++it) {
    int i = it * 512 + t;
    int nn = i >> 4, c16 = i & 15;
    int n = n0 + nn;
    int h = n >> 6, w = n & 63;
    short8 av = *(const short8*)(aws + ((size_t)((brel * 64 + w) * 256 + h)) * 128 + c16 * 8);
    *(short8*)(AS + adr_s(nn, c16 * 8)) = av;
  }
  __syncthreads();

  const int strip = wvid * 16;
  const unsigned short* wfcb = wb + 3 * 16384;
  short8 wf[4];
#pragma unroll
  for (int kk = 0; kk < 4; ++kk)
    wf[kk] = *(const short8*)(wfcb + (strip + l16) * 128 + kk * 32 + g4 * 8);
  float bv4[4];
#pragma unroll
  for (int r = 0; r < 4; ++r) bv4[r] = bfc[strip + g4 * 4 + r];

#pragma unroll
  for (int nt = 0; nt < 16; ++nt) {
    f32x4 acc = {0.f, 0.f, 0.f, 0.f};
#pragma unroll
    for (int kk = 0; kk < 4; ++kk) {
      short8 ab = ldsf(AS, adr_s(nt * 16 + l16, kk * 32 + g4 * 8));
      MFMA16(acc, wf[kk], ab);
    }
#pragma unroll
    for (int r = 0; r < 4; ++r) {
      int o = strip + g4 * 4 + r;
      out[(size_t)(b * 128 + o) * 16384 + n0 + nt * 16 + l16] = fmaxf(acc[r] + bv4[r], 0.f);
    }
  }
}

extern "C" void kernel_launch(void* const* d_in, const int* in_sizes, int n_in,
                              void* d_out, int out_size, void* d_ws, size_t ws_size,
                              hipStream_t stream) {
  const float* rep = (const float*)d_in[0];
  const float* wq  = (const float*)d_in[1];
  const float* bq  = (const float*)d_in[2];
  const float* wk  = (const float*)d_in[3];
  const float* bk  = (const float*)d_in[4];
  const float* wv  = (const float*)d_in[5];
  const float* bv  = (const float*)d_in[6];
  const float* wfc = (const float*)d_in[7];
  const float* bfc = (const float*)d_in[8];
  float* out = (float*)d_out;
  (void)in_sizes; (void)n_in; (void)out_size;

  hipFuncSetAttribute((const void*)k1_qkv,  hipFuncAttributeMaxDynamicSharedMemorySize, 40 * 1024);
  hipFuncSetAttribute((const void*)k2_attn, hipFuncAttributeMaxDynamicSharedMemorySize, 144 * 1024);
  hipFuncSetAttribute((const void*)k3_conv, hipFuncAttributeMaxDynamicSharedMemorySize, 64 * 1024);

  const size_t wb_bytes = 4 * 16384 * 2;          // 128 KB bf16 weights
  const size_t per_b = (size_t)16384 * 128 * 2;   // 4 MiB per array per b
  if (ws_size < wb_bytes + 4 * per_b) return;     // needs >= ~16.1 MB
  size_t nb_max = (ws_size - wb_bytes) / (4 * per_b);
  int nb = (int)(nb_max < 16 ? nb_max : 16);

  char* ws = (char*)d_ws;
  unsigned short* qws = (unsigned short*)(ws);
  unsigned short* kws = (unsigned short*)(ws + (size_t)nb * per_b);
  unsigned short* vws = (unsigned short*)(ws + (size_t)nb * per_b * 2);
  unsigned short* aws = (unsigned short*)(ws + (size_t)nb * per_b * 3);
  unsigned short* wb  = (unsigned short*)(ws + (size_t)nb * per_b * 4);

  k0_wcvt<<<dim3(64), dim3(256), 0, stream>>>(wq, wk, wv, wfc, wb);

  for (int b0 = 0; b0 < 16; b0 += nb) {
    int nbc = (16 - b0) < nb ? (16 - b0) : nb;
    k1_qkv<<<dim3(nbc * 128), dim3(512), 40 * 1024, stream>>>(
        rep, wb, bq, bk, bv, qws, kws, vws, b0);
    k2_attn<<<dim3(nbc * 64), dim3(512), 144 * 1024, stream>>>(qws, kws, vws, aws);
    k3_conv<<<dim3(nbc * 64), dim3(512), 64 * 1024, stream>>>(aws, wb, bfc, out, b0);
  }
}